// Round 12
// baseline (1254.109 us; speedup 1.0000x reference)
//
#include <hip/hip_runtime.h>
#include <math.h>

#define NB   64
#define SS   96
#define EE   300
#define DD   512
#define HH   256
#define SELD 128
#define CK   1280   // 5*H
#define MLPD 1024
#define NCLS 3
#define RB   97     // state rows per batch: 96 initial + 1 spare (freed-row recycling)

// ---------------- transpose W_sel1 [e][k] -> [e4][k] float4 (4 consecutive e rows at col k) ------
__global__ void k_trans_sel(const float* __restrict__ Ws, float* __restrict__ Ws4) {
    int e4 = blockIdx.x;            // 0..127
    int k = threadIdx.x;            // 0..127
    float4 v;
    v.x = Ws[(4 * e4 + 0) * SELD + k];
    v.y = Ws[(4 * e4 + 1) * SELD + k];
    v.z = Ws[(4 * e4 + 2) * SELD + k];
    v.w = Ws[(4 * e4 + 3) * SELD + k];
    ((float4*)Ws4)[e4 * SELD + k] = v;
}

// ---------------- encode v7: 1536 blocks (b x 6 s-tiles x 4 col-quarters), 1 s x 8 cols/thread --
__global__ __launch_bounds__(256) void k_encode(const int* __restrict__ sent,
                                                const float* __restrict__ emb,
                                                const float* __restrict__ Wenc,
                                                const float* __restrict__ benc,
                                                float* __restrict__ state) {
    int bi = blockIdx.x;
    int b = bi / 24, rem = bi % 24, tile = rem >> 2, ch = rem & 3;
    int s0 = tile * 16, col0 = ch * 128;
    __shared__ int tok[16];
    __shared__ __align__(16) float elds[16 * 300];
    int tid = threadIdx.x;
    if (tid < 16) tok[tid] = sent[b * SS + s0 + tid];
    __syncthreads();
    {
        const float4* e4p = (const float4*)emb;
        float4* l4s = (float4*)elds;
        for (int i4 = tid; i4 < 16 * 75; i4 += 256) {
            int s = i4 / 75, r = i4 - s * 75;
            l4s[i4] = e4p[(size_t)tok[s] * 75 + r];
        }
    }
    __syncthreads();
    int cg = tid & 15, sg = tid >> 4;            // 16 col-octets x 16 sents
    int colb = col0 + cg * 8;
    float4 aA = *(const float4*)&benc[colb];
    float4 aB = *(const float4*)&benc[colb + 4];
    const float4* l4 = (const float4*)elds + sg * 75;
    for (int e4 = 0; e4 < 75; e4++) {
        float4 wA[4], wB[4];
#pragma unroll
        for (int j = 0; j < 4; j++) {
            const float* wr = Wenc + (size_t)(4 * e4 + j) * DD + colb;
            wA[j] = *(const float4*)wr;
            wB[j] = *(const float4*)(wr + 4);
        }
        float4 xv = l4[e4];
        aA.x += xv.x * wA[0].x + xv.y * wA[1].x + xv.z * wA[2].x + xv.w * wA[3].x;
        aA.y += xv.x * wA[0].y + xv.y * wA[1].y + xv.z * wA[2].y + xv.w * wA[3].y;
        aA.z += xv.x * wA[0].z + xv.y * wA[1].z + xv.z * wA[2].z + xv.w * wA[3].z;
        aA.w += xv.x * wA[0].w + xv.y * wA[1].w + xv.z * wA[2].w + xv.w * wA[3].w;
        aB.x += xv.x * wB[0].x + xv.y * wB[1].x + xv.z * wB[2].x + xv.w * wB[3].x;
        aB.y += xv.x * wB[0].y + xv.y * wB[1].y + xv.z * wB[2].y + xv.w * wB[3].y;
        aB.z += xv.x * wB[0].z + xv.y * wB[1].z + xv.z * wB[2].z + xv.w * wB[3].z;
        aB.w += xv.x * wB[0].w + xv.y * wB[1].w + xv.z * wB[2].w + xv.w * wB[3].w;
    }
    {
        float* dst = state + ((size_t)b * RB + s0 + sg) * DD + colb;
        *(float4*)dst = aA;
        *(float4*)(dst + 4) = aB;
    }
}

// ---------------- initial logits (R8, proven) + folded bookkeeping init --------------------------
__global__ __launch_bounds__(256) void k_logits0(const float* __restrict__ state,
                                                 const float* __restrict__ Ws4,
                                                 const float* __restrict__ bs1,
                                                 const float* __restrict__ Ws2,
                                                 const float* __restrict__ bs2,
                                                 float* __restrict__ logits,
                                                 int* __restrict__ acts,
                                                 int* __restrict__ rec) {
    int b = blockIdx.x / 5, tile = blockIdx.x % 5, p0 = tile * 19;
    __shared__ __align__(16) float hl[20 * 256];
    __shared__ float part[2][2][10];
    int tid = threadIdx.x;
    if (tile == 0) {                              // parity-0 bookkeeping init
        if (tid < SS) acts[b * SS + tid] = tid;
        if (tid == 0) {
            int* r = rec + b * 4;
            r[0] = 0; r[1] = 0; r[2] = 0; r[3] = SS;
        }
    }
    for (int i = tid; i < 20 * 256; i += 256) {
        int r = i >> 8, c = i & 255;
        hl[i] = state[((size_t)b * RB + p0 + r) * DD + HH + c];
    }
    __syncthreads();
    int k = tid & 127, ph = tid >> 7;
    int npair = ph ? 9 : 10, pbase = ph * 10;
    float acc[10];
#pragma unroll
    for (int pp = 0; pp < 10; pp++) acc[pp] = 0.f;
    const float4* W4 = (const float4*)Ws4;
    const float4* h4 = (const float4*)hl;
    for (int e4 = 0; e4 < 128; e4++) {
        float4 w = W4[e4 * SELD + k];
#pragma unroll
        for (int pp = 0; pp < 10; pp++) {
            float4 x = h4[(pbase + pp) * 64 + e4];
            acc[pp] += x.x * w.x + x.y * w.y + x.z * w.z + x.w * w.w;
        }
    }
    float b1 = bs1[k], w2 = Ws2[k];
    int wid = (tid >> 6) & 1, lane = tid & 63;
#pragma unroll
    for (int pp = 0; pp < 10; pp++) {
        float y = (pp < npair) ? tanhf(acc[pp] + b1) * w2 : 0.f;
        for (int off = 32; off >= 1; off >>= 1) y += __shfl_down(y, off);
        if (lane == 0 && pp < npair) part[ph][wid][pp] = y;
    }
    __syncthreads();
    if (tid < 19) {
        int ph2 = tid / 10, pp = tid - ph2 * 10;
        logits[b * SS + p0 + tid] = part[ph2][0][pp] + part[ph2][1][pp] + bs2[0];
    }
}

// ---------------- fused step kernel v8: R11 base + role-split sel-partial tail -------------------
// 256 blocks = 16 bg x 16 ut; 640 threads; 4 batches/block.
// PselT layout per (parity,b): [pair(2)][k(128)][ut(16)] floats.
// Static sel halves (lm1/r2 inputs) computed by threads 384..639 in parallel with the K-reduce;
// only hn-dependent halves remain after gates. One barrier + ppex round-trip removed.
__global__ __launch_bounds__(640) void k_step(const float* __restrict__ Wc,
                                              const float* __restrict__ bcomp,
                                              const float* __restrict__ Ws4,
                                              const float* __restrict__ bs1,
                                              const float* __restrict__ Ws2,
                                              const float* __restrict__ bs2,
                                              float* __restrict__ logits,
                                              int* __restrict__ acts,
                                              int* __restrict__ rec,
                                              int* __restrict__ nlUsed,
                                              float* __restrict__ PselT,
                                              float* __restrict__ state, int t) {
    int bg = blockIdx.x & 15, ut = blockIdx.x >> 4;
    int tid = threadIdx.x, w = tid >> 6, lane = tid & 63;
    int n = SS - t, p = t & 1, np = p ^ 1;

    __shared__ float lgl[4][SS];
    __shared__ int   acl[4][SS];
    __shared__ int   recl[4][8];                 // idx,l,r,nl,lm1,r2,v0,v1
    __shared__ float cl[4][16], cr[4][16], lm1s[4][16], r2s[4][16], hn[4][16];
    __shared__ __align__(16) float4 sp4[4][20][33];
    __shared__ float a_l[4][5][16];
    __shared__ float pstat[4][2][SELD];          // [b][pair][k] static halves

    // ---- prefetch Ws4 fragments per role ----
    // dynamic (tid<256): pair dh=tid>>7, hn-half -> W half = dh^1
    // static (tid>=384): role r=tid-384, pair sh=r>>7, W half = sh
    float4 pw0, pw1, pw2, pw3;
    {
        int role = (tid < 256) ? tid : ((tid >= 384) ? (tid - 384) : 0);
        int kk = role & 127, rh = role >> 7;
        int half = (tid < 256) ? (rh ^ 1) : rh;
        int e4base = half * 64 + ut * 4;
        const float4* W4 = (const float4*)Ws4;
        pw0 = W4[(size_t)(e4base + 0) * SELD + kk];
        pw1 = W4[(size_t)(e4base + 1) * SELD + kk];
        pw2 = W4[(size_t)(e4base + 2) * SELD + kk];
        pw3 = W4[(size_t)(e4base + 3) * SELD + kk];
    }

    // ---- merged phases 1+2: hole refresh in registers, patch, argmax ----
    if (tid < 256) {
        int b = bg * 4 + w;
        const float* lgp = logits + ((size_t)p * NB + b) * SS;
        const int* acp = acts + ((size_t)p * NB + b) * SS;
        int4 r4 = *(const int4*)(rec + ((size_t)p * NB + b) * 4);
        int pidx = r4.x, pv0 = r4.y, pv1 = r4.z, freerow = r4.w;
        int j0 = lane, j1 = lane + 64;
        float x0v = (j0 <= n - 2) ? lgp[j0] : -3.0e38f;
        float x1v = (j1 <= n - 2) ? lgp[j1] : -3.0e38f;
        acl[w][j0] = acp[j0];
        if (j1 < SS) acl[w][j1] = acp[j1];
        if (t > 0 && (pv0 | pv1)) {
            float bs2v = bs2[0];
            float sA0 = bs1[lane], sA1 = bs1[lane + 64];
            float sB0 = sA0, sB1 = sA1;
            const float4* Pb4 = (const float4*)(PselT + (size_t)(p * NB + b) * 2 * 2048);
            float4 vA0, vA1, vB0, vB1;
#pragma unroll
            for (int c = 0; c < 4; c++) {
                vA0 = Pb4[lane * 4 + c];
                vA1 = Pb4[(lane + 64) * 4 + c];
                vB0 = Pb4[512 + lane * 4 + c];
                vB1 = Pb4[512 + (lane + 64) * 4 + c];
                sA0 += vA0.x + vA0.y + vA0.z + vA0.w;
                sA1 += vA1.x + vA1.y + vA1.z + vA1.w;
                sB0 += vB0.x + vB0.y + vB0.z + vB0.w;
                sB1 += vB1.x + vB1.y + vB1.z + vB1.w;
            }
            float yA = tanhf(sA0) * Ws2[lane] + tanhf(sA1) * Ws2[lane + 64];
            float yB = tanhf(sB0) * Ws2[lane] + tanhf(sB1) * Ws2[lane + 64];
#pragma unroll
            for (int off = 1; off < 64; off <<= 1) {
                yA += __shfl_xor(yA, off);
                yB += __shfl_xor(yB, off);
            }
            yA += bs2v; yB += bs2v;
            if (pv0) { if (j0 == pidx - 1) x0v = yA; if (j1 == pidx - 1) x1v = yA; }
            if (pv1) { if (j0 == pidx)     x0v = yB; if (j1 == pidx)     x1v = yB; }
        }
        if (j0 <= n - 2) lgl[w][j0] = x0v;
        if (j1 <= n - 2) lgl[w][j1] = x1v;
        float v = x0v; int i = j0;
        if (x1v > v) { v = x1v; i = j1; }
#pragma unroll
        for (int off = 1; off < 64; off <<= 1) {
            float ov = __shfl_xor(v, off);
            int oi = __shfl_xor(i, off);
            if (ov > v || (ov == v && oi < i)) { v = ov; i = oi; }
        }
        if (lane == 0) {
            int idx2 = i, l = acl[w][idx2], r = acl[w][idx2 + 1];
            int v0 = (idx2 >= 1), v1 = (idx2 <= n - 3);
            recl[w][0] = idx2; recl[w][1] = l; recl[w][2] = r; recl[w][3] = freerow;
            recl[w][4] = v0 ? acl[w][idx2 - 1] : 0;
            recl[w][5] = v1 ? acl[w][idx2 + 2] : 0;
            recl[w][6] = v0; recl[w][7] = v1;
        }
    }
    __syncthreads();

    // ---- stage small slices (c of l/r; h-slices of lm1/r2) ----
    if (tid < 256) {
        int which = tid >> 6, b2 = (tid >> 4) & 3, u = tid & 15;
        const float* sb = state + (size_t)(bg * 4 + b2) * RB * DD;
        if (which == 0)      cl[b2][u]   = sb[(size_t)recl[b2][1] * DD + ut * 16 + u];
        else if (which == 1) cr[b2][u]   = sb[(size_t)recl[b2][2] * DD + ut * 16 + u];
        else if (which == 2) lm1s[b2][u] = sb[(size_t)recl[b2][4] * DD + HH + ut * 16 + u];
        else                 r2s[b2][u]  = sb[(size_t)recl[b2][5] * DD + HH + ut * 16 + u];
    }

    // ---- bookkeeping into parity t+1 (ut==0 blocks; overlaps matvec) ----
    if (ut == 0 && tid < 256) {
        int b = bg * 4 + w;
        int idx = recl[w][0], l = recl[w][1], nl = recl[w][3];
        int* acn = acts + ((size_t)np * NB + b) * SS;
        float* lgn = logits + ((size_t)np * NB + b) * SS;
        for (int j = lane; j <= n - 2; j += 64)
            acn[j] = (j < idx) ? acl[w][j] : ((j == idx) ? nl : acl[w][j + 1]);
        for (int j = lane; j <= n - 3; j += 64)
            if (j != idx - 1 && j != idx)
                lgn[j] = (j < idx - 1) ? lgl[w][j] : lgl[w][j + 1];
        if (lane == 0) {
            int* rn = rec + ((size_t)np * NB + b) * 4;
            rn[0] = idx; rn[1] = recl[w][6]; rn[2] = recl[w][7]; rn[3] = l;
            nlUsed[b] = nl;
        }
    }

    // ---- compose matvec: thread = (ks:32, cq:20); 4 batches in regs ----
    {
        int ks = tid / 20, cq = tid - (tid / 20) * 20;
        int g = cq >> 2, q = cq & 3;
        int colb = g * 256 + ut * 16 + q * 4;
        int hoff = (ks & 15) * 4;
        bool leftHalf = (ks < 16);
        const float4* xp0 = (const float4*)(state + ((size_t)(bg * 4 + 0) * RB +
                              (leftHalf ? recl[0][1] : recl[0][2])) * DD + HH) + hoff;
        const float4* xp1 = (const float4*)(state + ((size_t)(bg * 4 + 1) * RB +
                              (leftHalf ? recl[1][1] : recl[1][2])) * DD + HH) + hoff;
        const float4* xp2 = (const float4*)(state + ((size_t)(bg * 4 + 2) * RB +
                              (leftHalf ? recl[2][1] : recl[2][2])) * DD + HH) + hoff;
        const float4* xp3 = (const float4*)(state + ((size_t)(bg * 4 + 3) * RB +
                              (leftHalf ? recl[3][1] : recl[3][2])) * DD + HH) + hoff;
        const float* wb = Wc + (size_t)(ks * 16) * CK + colb;
        float4 a0 = make_float4(0.f, 0.f, 0.f, 0.f);
        float4 a1 = a0, a2 = a0, a3 = a0;
#pragma unroll
        for (int i4 = 0; i4 < 4; i4++) {
            float4 xv0 = xp0[i4], xv1 = xp1[i4], xv2 = xp2[i4], xv3 = xp3[i4];
            const float* wr = wb + (size_t)(i4 * 4) * CK;
            float4 w0 = *(const float4*)(wr);
            float4 w1 = *(const float4*)(wr + CK);
            float4 w2v = *(const float4*)(wr + 2 * CK);
            float4 w3v = *(const float4*)(wr + 3 * CK);
            a0.x += xv0.x * w0.x + xv0.y * w1.x + xv0.z * w2v.x + xv0.w * w3v.x;
            a0.y += xv0.x * w0.y + xv0.y * w1.y + xv0.z * w2v.y + xv0.w * w3v.y;
            a0.z += xv0.x * w0.z + xv0.y * w1.z + xv0.z * w2v.z + xv0.w * w3v.z;
            a0.w += xv0.x * w0.w + xv0.y * w1.w + xv0.z * w2v.w + xv0.w * w3v.w;
            a1.x += xv1.x * w0.x + xv1.y * w1.x + xv1.z * w2v.x + xv1.w * w3v.x;
            a1.y += xv1.x * w0.y + xv1.y * w1.y + xv1.z * w2v.y + xv1.w * w3v.y;
            a1.z += xv1.x * w0.z + xv1.y * w1.z + xv1.z * w2v.z + xv1.w * w3v.z;
            a1.w += xv1.x * w0.w + xv1.y * w1.w + xv1.z * w2v.w + xv1.w * w3v.w;
            a2.x += xv2.x * w0.x + xv2.y * w1.x + xv2.z * w2v.x + xv2.w * w3v.x;
            a2.y += xv2.x * w0.y + xv2.y * w1.y + xv2.z * w2v.y + xv2.w * w3v.y;
            a2.z += xv2.x * w0.z + xv2.y * w1.z + xv2.z * w2v.z + xv2.w * w3v.z;
            a2.w += xv2.x * w0.w + xv2.y * w1.w + xv2.z * w2v.w + xv2.w * w3v.w;
            a3.x += xv3.x * w0.x + xv3.y * w1.x + xv3.z * w2v.x + xv3.w * w3v.x;
            a3.y += xv3.x * w0.y + xv3.y * w1.y + xv3.z * w2v.y + xv3.w * w3v.y;
            a3.z += xv3.x * w0.z + xv3.y * w1.z + xv3.z * w2v.z + xv3.w * w3v.z;
            a3.w += xv3.x * w0.w + xv3.y * w1.w + xv3.z * w2v.w + xv3.w * w3v.w;
        }
        sp4[0][cq][ks] = a0;
        sp4[1][cq][ks] = a1;
        sp4[2][cq][ks] = a2;
        sp4[3][cq][ks] = a3;
    }
    __syncthreads();

    // ---- K-reduce (tid<320) IN PARALLEL WITH static sel halves (tid>=384) ----
    if (tid < 320) {
        int b = tid / 80, colIdx = tid % 80;
        int g = colIdx >> 4, u = colIdx & 15;
        int cq = colIdx >> 2, e = colIdx & 3;
        float a = 0.f;
#pragma unroll
        for (int ks2 = 0; ks2 < 32; ks2++) a += ((const float*)&sp4[b][cq][ks2])[e];
        a_l[b][g][u] = a + bcomp[g * 256 + ut * 16 + u];
    } else if (tid >= 384) {
        int r = tid - 384, kk = r & 127, sh = r >> 7;   // sh==pair: 0->lm1 half, 1->r2 half
#pragma unroll
        for (int b4 = 0; b4 < 4; b4++) {
            const float* xs = sh ? r2s[b4] : lm1s[b4];
            float s = pw0.x * xs[0] + pw0.y * xs[1] + pw0.z * xs[2] + pw0.w * xs[3]
                    + pw1.x * xs[4] + pw1.y * xs[5] + pw1.z * xs[6] + pw1.w * xs[7]
                    + pw2.x * xs[8] + pw2.y * xs[9] + pw2.z * xs[10] + pw2.w * xs[11]
                    + pw3.x * xs[12] + pw3.y * xs[13] + pw3.z * xs[14] + pw3.w * xs[15];
            pstat[b4][sh][kk] = s;
        }
    }
    __syncthreads();

    // ---- gates + write composed c,h into fresh row ----
    if (tid < 64) {
        int b = tid >> 4, u = tid & 15;
        float ai = a_l[b][0][u], afl = a_l[b][1][u], afr = a_l[b][2][u];
        float ao = a_l[b][3][u], agc = a_l[b][4][u];
        float si  = 1.f / (1.f + expf(-ai));
        float sfl = 1.f / (1.f + expf(-afl));
        float sfr = 1.f / (1.f + expf(-afr));
        float so  = 1.f / (1.f + expf(-ao));
        float cv = sfl * cl[b][u] + sfr * cr[b][u] + si * tanhf(agc);
        float hv = so * tanhf(cv);
        float* sb = state + (size_t)(bg * 4 + b) * RB * DD;
        int nl = recl[b][3];
        sb[(size_t)nl * DD + ut * 16 + u] = cv;
        sb[(size_t)nl * DD + HH + ut * 16 + u] = hv;
        hn[b][u] = hv;
    }
    __syncthreads();

    // ---- dynamic (hn) sel halves + combine + write PselT ----
    if (tid < 256) {
        int kk = tid & 127, dh = tid >> 7;           // dh == pair index
#pragma unroll
        for (int b4 = 0; b4 < 4; b4++) {
            const float* xh = hn[b4];
            float d = pw0.x * xh[0] + pw0.y * xh[1] + pw0.z * xh[2] + pw0.w * xh[3]
                    + pw1.x * xh[4] + pw1.y * xh[5] + pw1.z * xh[6] + pw1.w * xh[7]
                    + pw2.x * xh[8] + pw2.y * xh[9] + pw2.z * xh[10] + pw2.w * xh[11]
                    + pw3.x * xh[12] + pw3.y * xh[13] + pw3.z * xh[14] + pw3.w * xh[15];
            int b = bg * 4 + b4;
            PselT[((size_t)(np * NB + b) * 2 + dh) * 2048 + kk * 16 + ut] =
                d + pstat[b4][dh][kk];
        }
    }
}

// ---------------- MLP head, column-parallel ------------------------------------------------------
__global__ __launch_bounds__(256) void k_mlp1(const float* __restrict__ state,
                                              const int* __restrict__ nlUsed,
                                              const float* __restrict__ Wm1,
                                              const float* __restrict__ bm1,
                                              float* __restrict__ x1g) {
    int b = blockIdx.x >> 2, q = blockIdx.x & 3, tid = threadIdx.x;
    int col = q * 256 + tid;
    __shared__ float x0[HH];
    int root = nlUsed[b];
    x0[tid] = state[((size_t)b * RB + root) * DD + HH + tid];
    __syncthreads();
    float acc = bm1[col];
    for (int e = 0; e < HH; e++) acc += x0[e] * Wm1[(size_t)e * MLPD + col];
    x1g[(size_t)b * MLPD + col] = fmaxf(acc, 0.f);
}

// mlp2 v2: 2 batches/block amortize each Wm2 read x2. 256 blocks = 32 b-pairs x 8 col-slices.
__global__ __launch_bounds__(128) void k_mlp2(const float* __restrict__ x1g,
                                              const float* __restrict__ Wm2,
                                              const float* __restrict__ bm2,
                                              float* __restrict__ x2g) {
    int bp = blockIdx.x >> 3, q = blockIdx.x & 7, tid = threadIdx.x;
    int col = q * 128 + tid;
    __shared__ __align__(16) float x1[2][MLPD];
    for (int i = tid; i < 512; i += 128) {
        int bb = i >> 8, r = i & 255;
        ((float4*)x1[bb])[r] = ((const float4*)(x1g + (size_t)(bp * 2 + bb) * MLPD))[r];
    }
    __syncthreads();
    float acc0 = bm2[col], acc1 = acc0;
    for (int e = 0; e < MLPD; e++) {
        float wv = Wm2[(size_t)e * MLPD + col];
        acc0 += x1[0][e] * wv;
        acc1 += x1[1][e] * wv;
    }
    x2g[(size_t)(bp * 2 + 0) * MLPD + col] = fmaxf(acc0, 0.f);
    x2g[(size_t)(bp * 2 + 1) * MLPD + col] = fmaxf(acc1, 0.f);
}

__global__ __launch_bounds__(256) void k_mlp3(const float* __restrict__ x2g,
                                              const float* __restrict__ Wout,
                                              const float* __restrict__ bout,
                                              float* __restrict__ out) {
    int b = blockIdx.x, tid = threadIdx.x;
    __shared__ __align__(16) float x2[MLPD];
    __shared__ float red3[3][256];
    ((float4*)x2)[tid] = ((const float4*)(x2g + (size_t)b * MLPD))[tid];
    __syncthreads();
    float p0 = 0.f, p1 = 0.f, p2 = 0.f;
    for (int e = tid; e < MLPD; e += 256) {
        float x = x2[e];
        p0 += x * Wout[e * NCLS + 0];
        p1 += x * Wout[e * NCLS + 1];
        p2 += x * Wout[e * NCLS + 2];
    }
    red3[0][tid] = p0; red3[1][tid] = p1; red3[2][tid] = p2;
    __syncthreads();
    for (int sdd = 128; sdd >= 1; sdd >>= 1) {
        if (tid < sdd) {
            red3[0][tid] += red3[0][tid + sdd];
            red3[1][tid] += red3[1][tid + sdd];
            red3[2][tid] += red3[2][tid + sdd];
        }
        __syncthreads();
    }
    if (tid < NCLS) out[b * NCLS + tid] = red3[tid][0] + bout[tid];
}

extern "C" void kernel_launch(void* const* d_in, const int* in_sizes, int n_in,
                              void* d_out, int out_size, void* d_ws, size_t ws_size,
                              hipStream_t stream) {
    const int*   sent  = (const int*)d_in[0];
    // d_in[1] = transitions: unused by the reference
    const float* emb   = (const float*)d_in[2];
    const float* Wenc  = (const float*)d_in[3];
    const float* benc  = (const float*)d_in[4];
    const float* Wcomp = (const float*)d_in[5];
    const float* bcomp = (const float*)d_in[6];
    const float* Wsel1 = (const float*)d_in[7];
    const float* bs1   = (const float*)d_in[8];
    const float* Ws2   = (const float*)d_in[9];
    const float* bs2   = (const float*)d_in[10];
    const float* Wm1   = (const float*)d_in[11];
    const float* bm1   = (const float*)d_in[12];
    const float* Wm2   = (const float*)d_in[13];
    const float* bm2   = (const float*)d_in[14];
    const float* Wout  = (const float*)d_in[15];
    const float* bout  = (const float*)d_in[16];
    float* out = (float*)d_out;

    float* ws     = (float*)d_ws;
    float* state  = ws;                              // 3,178,496 f32
    float* Ws14   = ws + 3178496;                    // 65,536
    float* logits = ws + 3244032;                    // 2*64*96 = 12,288 (ping-pong)
    int*   acts   = (int*)(ws + 3256320);            // 12,288 ints (ping-pong)
    int*   rec    = (int*)(ws + 3268608);            // 512 ints (ping-pong)
    int*   nlUsed = (int*)(ws + 3269120);            // 64 ints
    float* PselT  = ws + 3269184;                    // 2*64*2*128*16 = 524,288 (ping-pong)
    float* x1g    = ws + 3269184;                    // alias: PselT dead after scan
    float* x2g    = ws + 3334720;                    // alias

    k_trans_sel<<<dim3(128), dim3(128), 0, stream>>>(Wsel1, Ws14);
    k_encode<<<dim3(NB * 24), dim3(256), 0, stream>>>(sent, emb, Wenc, benc, state);
    k_logits0<<<dim3(NB * 5), dim3(256), 0, stream>>>(state, Ws14, bs1, Ws2, bs2, logits,
                                                      acts, rec);

    for (int t = 0; t < SS - 1; t++)   // t = 0..94
        k_step<<<dim3(256), dim3(640), 0, stream>>>(Wcomp, bcomp, Ws14, bs1, Ws2, bs2,
                                                    logits, acts, rec, nlUsed, PselT, state, t);

    k_mlp1<<<dim3(NB * 4), dim3(256), 0, stream>>>(state, nlUsed, Wm1, bm1, x1g);
    k_mlp2<<<dim3(256), dim3(128), 0, stream>>>(x1g, Wm2, bm2, x2g);
    k_mlp3<<<dim3(NB), dim3(256), 0, stream>>>(x2g, Wout, bout, out);
}

// Round 13
// 1206.226 us; speedup vs baseline: 1.0397x; 1.0397x over previous
//
#include <hip/hip_runtime.h>
#include <math.h>

#define NB   64
#define SS   96
#define EE   300
#define DD   512
#define HH   256
#define SELD 128
#define CK   1280   // 5*H
#define MLPD 1024
#define NCLS 3
#define RB   97     // state rows per batch: 96 initial + 1 spare (freed-row recycling)

// ---------------- encode v6 (proven 72us) + folded W_sel1 transpose (blocks >= NB*12) -----------
__global__ __launch_bounds__(256) void k_encode(const int* __restrict__ sent,
                                                const float* __restrict__ emb,
                                                const float* __restrict__ Wenc,
                                                const float* __restrict__ benc,
                                                float* __restrict__ state,
                                                const float* __restrict__ Ws,
                                                float* __restrict__ Ws4) {
    int bi = blockIdx.x;
    int tid = threadIdx.x;
    if (bi >= NB * 12) {                          // W_sel1 transpose: 64 blocks x 2 e4-rows
        int e4 = (bi - NB * 12) * 2 + (tid >> 7);
        int k = tid & 127;
        float4 v;
        v.x = Ws[(4 * e4 + 0) * SELD + k];
        v.y = Ws[(4 * e4 + 1) * SELD + k];
        v.z = Ws[(4 * e4 + 2) * SELD + k];
        v.w = Ws[(4 * e4 + 3) * SELD + k];
        ((float4*)Ws4)[e4 * SELD + k] = v;
        return;
    }
    int b = bi / 12, rem = bi % 12, tile = rem >> 2, ch = rem & 3;
    int s0 = tile * 32, col0 = ch * 128;
    __shared__ int tok[32];
    __shared__ __align__(16) float elds[32 * 300];
    if (tid < 32) tok[tid] = sent[b * SS + s0 + tid];
    __syncthreads();
    {
        const float4* e4p = (const float4*)emb;
        float4* l4s = (float4*)elds;
        for (int i4 = tid; i4 < 32 * 75; i4 += 256) {
            int s = i4 / 75, r = i4 - s * 75;
            l4s[i4] = e4p[(size_t)tok[s] * 75 + r];
        }
    }
    __syncthreads();
    int cg = tid & 15, sg = tid >> 4;
    int colb = col0 + cg * 8, sb = sg * 2;
    float4 aA0, aA1, aB0, aB1;
    {
        float4 bA = *(const float4*)&benc[colb];
        float4 bB = *(const float4*)&benc[colb + 4];
        aA0 = bA; aA1 = bA; aB0 = bB; aB1 = bB;
    }
    const float4* l4 = (const float4*)elds;
    for (int e4 = 0; e4 < 75; e4++) {
        float4 wA[4], wB[4];
#pragma unroll
        for (int j = 0; j < 4; j++) {
            const float* wr = Wenc + (size_t)(4 * e4 + j) * DD + colb;
            wA[j] = *(const float4*)wr;
            wB[j] = *(const float4*)(wr + 4);
        }
        float4 x0 = l4[(sb + 0) * 75 + e4];
        float4 x1 = l4[(sb + 1) * 75 + e4];
        aA0.x += x0.x * wA[0].x + x0.y * wA[1].x + x0.z * wA[2].x + x0.w * wA[3].x;
        aA0.y += x0.x * wA[0].y + x0.y * wA[1].y + x0.z * wA[2].y + x0.w * wA[3].y;
        aA0.z += x0.x * wA[0].z + x0.y * wA[1].z + x0.z * wA[2].z + x0.w * wA[3].z;
        aA0.w += x0.x * wA[0].w + x0.y * wA[1].w + x0.z * wA[2].w + x0.w * wA[3].w;
        aB0.x += x0.x * wB[0].x + x0.y * wB[1].x + x0.z * wB[2].x + x0.w * wB[3].x;
        aB0.y += x0.x * wB[0].y + x0.y * wB[1].y + x0.z * wB[2].y + x0.w * wB[3].y;
        aB0.z += x0.x * wB[0].z + x0.y * wB[1].z + x0.z * wB[2].z + x0.w * wB[3].z;
        aB0.w += x0.x * wB[0].w + x0.y * wB[1].w + x0.z * wB[2].w + x0.w * wB[3].w;
        aA1.x += x1.x * wA[0].x + x1.y * wA[1].x + x1.z * wA[2].x + x1.w * wA[3].x;
        aA1.y += x1.x * wA[0].y + x1.y * wA[1].y + x1.z * wA[2].y + x1.w * wA[3].y;
        aA1.z += x1.x * wA[0].z + x1.y * wA[1].z + x1.z * wA[2].z + x1.w * wA[3].z;
        aA1.w += x1.x * wA[0].w + x1.y * wA[1].w + x1.z * wA[2].w + x1.w * wA[3].w;
        aB1.x += x1.x * wB[0].x + x1.y * wB[1].x + x1.z * wB[2].x + x1.w * wB[3].x;
        aB1.y += x1.x * wB[0].y + x1.y * wB[1].y + x1.z * wB[2].y + x1.w * wB[3].y;
        aB1.z += x1.x * wB[0].z + x1.y * wB[1].z + x1.z * wB[2].z + x1.w * wB[3].z;
        aB1.w += x1.x * wB[0].w + x1.y * wB[1].w + x1.z * wB[2].w + x1.w * wB[3].w;
    }
    {
        float* dst = state + ((size_t)b * RB + s0 + sb) * DD + colb;
        *(float4*)dst = aA0;
        *(float4*)(dst + 4) = aB0;
        dst += DD;
        *(float4*)dst = aA1;
        *(float4*)(dst + 4) = aB1;
    }
}

// ---------------- initial logits (R8, proven) + folded bookkeeping init --------------------------
__global__ __launch_bounds__(256) void k_logits0(const float* __restrict__ state,
                                                 const float* __restrict__ Ws4,
                                                 const float* __restrict__ bs1,
                                                 const float* __restrict__ Ws2,
                                                 const float* __restrict__ bs2,
                                                 float* __restrict__ logits,
                                                 int* __restrict__ acts,
                                                 int* __restrict__ rec) {
    int b = blockIdx.x / 5, tile = blockIdx.x % 5, p0 = tile * 19;
    __shared__ __align__(16) float hl[20 * 256];
    __shared__ float part[2][2][10];
    int tid = threadIdx.x;
    if (tile == 0) {                              // parity-0 bookkeeping init
        if (tid < SS) acts[b * SS + tid] = tid;
        if (tid == 0) {
            int* r = rec + b * 4;
            r[0] = 0; r[1] = 0; r[2] = 0; r[3] = SS;
        }
    }
    for (int i = tid; i < 20 * 256; i += 256) {
        int r = i >> 8, c = i & 255;
        hl[i] = state[((size_t)b * RB + p0 + r) * DD + HH + c];
    }
    __syncthreads();
    int k = tid & 127, ph = tid >> 7;
    int npair = ph ? 9 : 10, pbase = ph * 10;
    float acc[10];
#pragma unroll
    for (int pp = 0; pp < 10; pp++) acc[pp] = 0.f;
    const float4* W4 = (const float4*)Ws4;
    const float4* h4 = (const float4*)hl;
    for (int e4 = 0; e4 < 128; e4++) {
        float4 w = W4[e4 * SELD + k];
#pragma unroll
        for (int pp = 0; pp < 10; pp++) {
            float4 x = h4[(pbase + pp) * 64 + e4];
            acc[pp] += x.x * w.x + x.y * w.y + x.z * w.z + x.w * w.w;
        }
    }
    float b1 = bs1[k], w2 = Ws2[k];
    int wid = (tid >> 6) & 1, lane = tid & 63;
#pragma unroll
    for (int pp = 0; pp < 10; pp++) {
        float y = (pp < npair) ? tanhf(acc[pp] + b1) * w2 : 0.f;
        for (int off = 32; off >= 1; off >>= 1) y += __shfl_down(y, off);
        if (lane == 0 && pp < npair) part[ph][wid][pp] = y;
    }
    __syncthreads();
    if (tid < 19) {
        int ph2 = tid / 10, pp = tid - ph2 * 10;
        logits[b * SS + p0 + tid] = part[ph2][0][pp] + part[ph2][1][pp] + bs2[0];
    }
}

// ---------------- fused step kernel v8 (R12, kept): role-split sel-partial tail ------------------
// 256 blocks = 16 bg x 16 ut; 640 threads; 4 batches/block.
// PselT layout per (parity,b): [pair(2)][k(128)][ut(16)] floats.
__global__ __launch_bounds__(640) void k_step(const float* __restrict__ Wc,
                                              const float* __restrict__ bcomp,
                                              const float* __restrict__ Ws4,
                                              const float* __restrict__ bs1,
                                              const float* __restrict__ Ws2,
                                              const float* __restrict__ bs2,
                                              float* __restrict__ logits,
                                              int* __restrict__ acts,
                                              int* __restrict__ rec,
                                              int* __restrict__ nlUsed,
                                              float* __restrict__ PselT,
                                              float* __restrict__ state, int t) {
    int bg = blockIdx.x & 15, ut = blockIdx.x >> 4;
    int tid = threadIdx.x, w = tid >> 6, lane = tid & 63;
    int n = SS - t, p = t & 1, np = p ^ 1;

    __shared__ float lgl[4][SS];
    __shared__ int   acl[4][SS];
    __shared__ int   recl[4][8];                 // idx,l,r,nl,lm1,r2,v0,v1
    __shared__ float cl[4][16], cr[4][16], lm1s[4][16], r2s[4][16], hn[4][16];
    __shared__ __align__(16) float4 sp4[4][20][33];
    __shared__ float a_l[4][5][16];
    __shared__ float pstat[4][2][SELD];          // [b][pair][k] static halves

    // ---- prefetch Ws4 fragments per role ----
    float4 pw0, pw1, pw2, pw3;
    {
        int role = (tid < 256) ? tid : ((tid >= 384) ? (tid - 384) : 0);
        int kk = role & 127, rh = role >> 7;
        int half = (tid < 256) ? (rh ^ 1) : rh;
        int e4base = half * 64 + ut * 4;
        const float4* W4 = (const float4*)Ws4;
        pw0 = W4[(size_t)(e4base + 0) * SELD + kk];
        pw1 = W4[(size_t)(e4base + 1) * SELD + kk];
        pw2 = W4[(size_t)(e4base + 2) * SELD + kk];
        pw3 = W4[(size_t)(e4base + 3) * SELD + kk];
    }

    // ---- merged phases 1+2: hole refresh in registers, patch, argmax ----
    if (tid < 256) {
        int b = bg * 4 + w;
        const float* lgp = logits + ((size_t)p * NB + b) * SS;
        const int* acp = acts + ((size_t)p * NB + b) * SS;
        int4 r4 = *(const int4*)(rec + ((size_t)p * NB + b) * 4);
        int pidx = r4.x, pv0 = r4.y, pv1 = r4.z, freerow = r4.w;
        int j0 = lane, j1 = lane + 64;
        float x0v = (j0 <= n - 2) ? lgp[j0] : -3.0e38f;
        float x1v = (j1 <= n - 2) ? lgp[j1] : -3.0e38f;
        acl[w][j0] = acp[j0];
        if (j1 < SS) acl[w][j1] = acp[j1];
        if (t > 0 && (pv0 | pv1)) {
            float bs2v = bs2[0];
            float sA0 = bs1[lane], sA1 = bs1[lane + 64];
            float sB0 = sA0, sB1 = sA1;
            const float4* Pb4 = (const float4*)(PselT + (size_t)(p * NB + b) * 2 * 2048);
            float4 vA0, vA1, vB0, vB1;
#pragma unroll
            for (int c = 0; c < 4; c++) {
                vA0 = Pb4[lane * 4 + c];
                vA1 = Pb4[(lane + 64) * 4 + c];
                vB0 = Pb4[512 + lane * 4 + c];
                vB1 = Pb4[512 + (lane + 64) * 4 + c];
                sA0 += vA0.x + vA0.y + vA0.z + vA0.w;
                sA1 += vA1.x + vA1.y + vA1.z + vA1.w;
                sB0 += vB0.x + vB0.y + vB0.z + vB0.w;
                sB1 += vB1.x + vB1.y + vB1.z + vB1.w;
            }
            float yA = tanhf(sA0) * Ws2[lane] + tanhf(sA1) * Ws2[lane + 64];
            float yB = tanhf(sB0) * Ws2[lane] + tanhf(sB1) * Ws2[lane + 64];
#pragma unroll
            for (int off = 1; off < 64; off <<= 1) {
                yA += __shfl_xor(yA, off);
                yB += __shfl_xor(yB, off);
            }
            yA += bs2v; yB += bs2v;
            if (pv0) { if (j0 == pidx - 1) x0v = yA; if (j1 == pidx - 1) x1v = yA; }
            if (pv1) { if (j0 == pidx)     x0v = yB; if (j1 == pidx)     x1v = yB; }
        }
        if (j0 <= n - 2) lgl[w][j0] = x0v;
        if (j1 <= n - 2) lgl[w][j1] = x1v;
        float v = x0v; int i = j0;
        if (x1v > v) { v = x1v; i = j1; }
#pragma unroll
        for (int off = 1; off < 64; off <<= 1) {
            float ov = __shfl_xor(v, off);
            int oi = __shfl_xor(i, off);
            if (ov > v || (ov == v && oi < i)) { v = ov; i = oi; }
        }
        if (lane == 0) {
            int idx2 = i, l = acl[w][idx2], r = acl[w][idx2 + 1];
            int v0 = (idx2 >= 1), v1 = (idx2 <= n - 3);
            recl[w][0] = idx2; recl[w][1] = l; recl[w][2] = r; recl[w][3] = freerow;
            recl[w][4] = v0 ? acl[w][idx2 - 1] : 0;
            recl[w][5] = v1 ? acl[w][idx2 + 2] : 0;
            recl[w][6] = v0; recl[w][7] = v1;
        }
    }
    __syncthreads();

    // ---- stage small slices (c of l/r; h-slices of lm1/r2) ----
    if (tid < 256) {
        int which = tid >> 6, b2 = (tid >> 4) & 3, u = tid & 15;
        const float* sb = state + (size_t)(bg * 4 + b2) * RB * DD;
        if (which == 0)      cl[b2][u]   = sb[(size_t)recl[b2][1] * DD + ut * 16 + u];
        else if (which == 1) cr[b2][u]   = sb[(size_t)recl[b2][2] * DD + ut * 16 + u];
        else if (which == 2) lm1s[b2][u] = sb[(size_t)recl[b2][4] * DD + HH + ut * 16 + u];
        else                 r2s[b2][u]  = sb[(size_t)recl[b2][5] * DD + HH + ut * 16 + u];
    }

    // ---- bookkeeping into parity t+1 (ut==0 blocks; overlaps matvec) ----
    if (ut == 0 && tid < 256) {
        int b = bg * 4 + w;
        int idx = recl[w][0], l = recl[w][1], nl = recl[w][3];
        int* acn = acts + ((size_t)np * NB + b) * SS;
        float* lgn = logits + ((size_t)np * NB + b) * SS;
        for (int j = lane; j <= n - 2; j += 64)
            acn[j] = (j < idx) ? acl[w][j] : ((j == idx) ? nl : acl[w][j + 1]);
        for (int j = lane; j <= n - 3; j += 64)
            if (j != idx - 1 && j != idx)
                lgn[j] = (j < idx - 1) ? lgl[w][j] : lgl[w][j + 1];
        if (lane == 0) {
            int* rn = rec + ((size_t)np * NB + b) * 4;
            rn[0] = idx; rn[1] = recl[w][6]; rn[2] = recl[w][7]; rn[3] = l;
            nlUsed[b] = nl;
        }
    }

    // ---- compose matvec: thread = (ks:32, cq:20); 4 batches in regs ----
    {
        int ks = tid / 20, cq = tid - (tid / 20) * 20;
        int g = cq >> 2, q = cq & 3;
        int colb = g * 256 + ut * 16 + q * 4;
        int hoff = (ks & 15) * 4;
        bool leftHalf = (ks < 16);
        const float4* xp0 = (const float4*)(state + ((size_t)(bg * 4 + 0) * RB +
                              (leftHalf ? recl[0][1] : recl[0][2])) * DD + HH) + hoff;
        const float4* xp1 = (const float4*)(state + ((size_t)(bg * 4 + 1) * RB +
                              (leftHalf ? recl[1][1] : recl[1][2])) * DD + HH) + hoff;
        const float4* xp2 = (const float4*)(state + ((size_t)(bg * 4 + 2) * RB +
                              (leftHalf ? recl[2][1] : recl[2][2])) * DD + HH) + hoff;
        const float4* xp3 = (const float4*)(state + ((size_t)(bg * 4 + 3) * RB +
                              (leftHalf ? recl[3][1] : recl[3][2])) * DD + HH) + hoff;
        const float* wb = Wc + (size_t)(ks * 16) * CK + colb;
        float4 a0 = make_float4(0.f, 0.f, 0.f, 0.f);
        float4 a1 = a0, a2 = a0, a3 = a0;
#pragma unroll
        for (int i4 = 0; i4 < 4; i4++) {
            float4 xv0 = xp0[i4], xv1 = xp1[i4], xv2 = xp2[i4], xv3 = xp3[i4];
            const float* wr = wb + (size_t)(i4 * 4) * CK;
            float4 w0 = *(const float4*)(wr);
            float4 w1 = *(const float4*)(wr + CK);
            float4 w2v = *(const float4*)(wr + 2 * CK);
            float4 w3v = *(const float4*)(wr + 3 * CK);
            a0.x += xv0.x * w0.x + xv0.y * w1.x + xv0.z * w2v.x + xv0.w * w3v.x;
            a0.y += xv0.x * w0.y + xv0.y * w1.y + xv0.z * w2v.y + xv0.w * w3v.y;
            a0.z += xv0.x * w0.z + xv0.y * w1.z + xv0.z * w2v.z + xv0.w * w3v.z;
            a0.w += xv0.x * w0.w + xv0.y * w1.w + xv0.z * w2v.w + xv0.w * w3v.w;
            a1.x += xv1.x * w0.x + xv1.y * w1.x + xv1.z * w2v.x + xv1.w * w3v.x;
            a1.y += xv1.x * w0.y + xv1.y * w1.y + xv1.z * w2v.y + xv1.w * w3v.y;
            a1.z += xv1.x * w0.z + xv1.y * w1.z + xv1.z * w2v.z + xv1.w * w3v.z;
            a1.w += xv1.x * w0.w + xv1.y * w1.w + xv1.z * w2v.w + xv1.w * w3v.w;
            a2.x += xv2.x * w0.x + xv2.y * w1.x + xv2.z * w2v.x + xv2.w * w3v.x;
            a2.y += xv2.x * w0.y + xv2.y * w1.y + xv2.z * w2v.y + xv2.w * w3v.y;
            a2.z += xv2.x * w0.z + xv2.y * w1.z + xv2.z * w2v.z + xv2.w * w3v.z;
            a2.w += xv2.x * w0.w + xv2.y * w1.w + xv2.z * w2v.w + xv2.w * w3v.w;
            a3.x += xv3.x * w0.x + xv3.y * w1.x + xv3.z * w2v.x + xv3.w * w3v.x;
            a3.y += xv3.x * w0.y + xv3.y * w1.y + xv3.z * w2v.y + xv3.w * w3v.y;
            a3.z += xv3.x * w0.z + xv3.y * w1.z + xv3.z * w2v.z + xv3.w * w3v.z;
            a3.w += xv3.x * w0.w + xv3.y * w1.w + xv3.z * w2v.w + xv3.w * w3v.w;
        }
        sp4[0][cq][ks] = a0;
        sp4[1][cq][ks] = a1;
        sp4[2][cq][ks] = a2;
        sp4[3][cq][ks] = a3;
    }
    __syncthreads();

    // ---- K-reduce (tid<320) IN PARALLEL WITH static sel halves (tid>=384) ----
    if (tid < 320) {
        int b = tid / 80, colIdx = tid % 80;
        int g = colIdx >> 4, u = colIdx & 15;
        int cq = colIdx >> 2, e = colIdx & 3;
        float a = 0.f;
#pragma unroll
        for (int ks2 = 0; ks2 < 32; ks2++) a += ((const float*)&sp4[b][cq][ks2])[e];
        a_l[b][g][u] = a + bcomp[g * 256 + ut * 16 + u];
    } else if (tid >= 384) {
        int r = tid - 384, kk = r & 127, sh = r >> 7;   // sh==pair: 0->lm1 half, 1->r2 half
#pragma unroll
        for (int b4 = 0; b4 < 4; b4++) {
            const float* xs = sh ? r2s[b4] : lm1s[b4];
            float s = pw0.x * xs[0] + pw0.y * xs[1] + pw0.z * xs[2] + pw0.w * xs[3]
                    + pw1.x * xs[4] + pw1.y * xs[5] + pw1.z * xs[6] + pw1.w * xs[7]
                    + pw2.x * xs[8] + pw2.y * xs[9] + pw2.z * xs[10] + pw2.w * xs[11]
                    + pw3.x * xs[12] + pw3.y * xs[13] + pw3.z * xs[14] + pw3.w * xs[15];
            pstat[b4][sh][kk] = s;
        }
    }
    __syncthreads();

    // ---- gates + write composed c,h into fresh row ----
    if (tid < 64) {
        int b = tid >> 4, u = tid & 15;
        float ai = a_l[b][0][u], afl = a_l[b][1][u], afr = a_l[b][2][u];
        float ao = a_l[b][3][u], agc = a_l[b][4][u];
        float si  = 1.f / (1.f + expf(-ai));
        float sfl = 1.f / (1.f + expf(-afl));
        float sfr = 1.f / (1.f + expf(-afr));
        float so  = 1.f / (1.f + expf(-ao));
        float cv = sfl * cl[b][u] + sfr * cr[b][u] + si * tanhf(agc);
        float hv = so * tanhf(cv);
        float* sb = state + (size_t)(bg * 4 + b) * RB * DD;
        int nl = recl[b][3];
        sb[(size_t)nl * DD + ut * 16 + u] = cv;
        sb[(size_t)nl * DD + HH + ut * 16 + u] = hv;
        hn[b][u] = hv;
    }
    __syncthreads();

    // ---- dynamic (hn) sel halves + combine + write PselT ----
    if (tid < 256) {
        int kk = tid & 127, dh = tid >> 7;           // dh == pair index
#pragma unroll
        for (int b4 = 0; b4 < 4; b4++) {
            const float* xh = hn[b4];
            float d = pw0.x * xh[0] + pw0.y * xh[1] + pw0.z * xh[2] + pw0.w * xh[3]
                    + pw1.x * xh[4] + pw1.y * xh[5] + pw1.z * xh[6] + pw1.w * xh[7]
                    + pw2.x * xh[8] + pw2.y * xh[9] + pw2.z * xh[10] + pw2.w * xh[11]
                    + pw3.x * xh[12] + pw3.y * xh[13] + pw3.z * xh[14] + pw3.w * xh[15];
            int b = bg * 4 + b4;
            PselT[((size_t)(np * NB + b) * 2 + dh) * 2048 + kk * 16 + ut] =
                d + pstat[b4][dh][kk];
        }
    }
}

// ---------------- MLP head, column-parallel ------------------------------------------------------
__global__ __launch_bounds__(256) void k_mlp1(const float* __restrict__ state,
                                              const int* __restrict__ nlUsed,
                                              const float* __restrict__ Wm1,
                                              const float* __restrict__ bm1,
                                              float* __restrict__ x1g) {
    int b = blockIdx.x >> 2, q = blockIdx.x & 3, tid = threadIdx.x;
    int col = q * 256 + tid;
    __shared__ float x0[HH];
    int root = nlUsed[b];
    x0[tid] = state[((size_t)b * RB + root) * DD + HH + tid];
    __syncthreads();
    float acc = bm1[col];
    for (int e = 0; e < HH; e++) acc += x0[e] * Wm1[(size_t)e * MLPD + col];
    x1g[(size_t)b * MLPD + col] = fmaxf(acc, 0.f);
}

// mlp2 v2: 2 batches/block amortize each Wm2 read x2. 256 blocks = 32 b-pairs x 8 col-slices.
__global__ __launch_bounds__(128) void k_mlp2(const float* __restrict__ x1g,
                                              const float* __restrict__ Wm2,
                                              const float* __restrict__ bm2,
                                              float* __restrict__ x2g) {
    int bp = blockIdx.x >> 3, q = blockIdx.x & 7, tid = threadIdx.x;
    int col = q * 128 + tid;
    __shared__ __align__(16) float x1[2][MLPD];
    for (int i = tid; i < 512; i += 128) {
        int bb = i >> 8, r = i & 255;
        ((float4*)x1[bb])[r] = ((const float4*)(x1g + (size_t)(bp * 2 + bb) * MLPD))[r];
    }
    __syncthreads();
    float acc0 = bm2[col], acc1 = acc0;
    for (int e = 0; e < MLPD; e++) {
        float wv = Wm2[(size_t)e * MLPD + col];
        acc0 += x1[0][e] * wv;
        acc1 += x1[1][e] * wv;
    }
    x2g[(size_t)(bp * 2 + 0) * MLPD + col] = fmaxf(acc0, 0.f);
    x2g[(size_t)(bp * 2 + 1) * MLPD + col] = fmaxf(acc1, 0.f);
}

__global__ __launch_bounds__(256) void k_mlp3(const float* __restrict__ x2g,
                                              const float* __restrict__ Wout,
                                              const float* __restrict__ bout,
                                              float* __restrict__ out) {
    int b = blockIdx.x, tid = threadIdx.x;
    __shared__ __align__(16) float x2[MLPD];
    __shared__ float red3[3][256];
    ((float4*)x2)[tid] = ((const float4*)(x2g + (size_t)b * MLPD))[tid];
    __syncthreads();
    float p0 = 0.f, p1 = 0.f, p2 = 0.f;
    for (int e = tid; e < MLPD; e += 256) {
        float x = x2[e];
        p0 += x * Wout[e * NCLS + 0];
        p1 += x * Wout[e * NCLS + 1];
        p2 += x * Wout[e * NCLS + 2];
    }
    red3[0][tid] = p0; red3[1][tid] = p1; red3[2][tid] = p2;
    __syncthreads();
    for (int sdd = 128; sdd >= 1; sdd >>= 1) {
        if (tid < sdd) {
            red3[0][tid] += red3[0][tid + sdd];
            red3[1][tid] += red3[1][tid + sdd];
            red3[2][tid] += red3[2][tid + sdd];
        }
        __syncthreads();
    }
    if (tid < NCLS) out[b * NCLS + tid] = red3[tid][0] + bout[tid];
}

extern "C" void kernel_launch(void* const* d_in, const int* in_sizes, int n_in,
                              void* d_out, int out_size, void* d_ws, size_t ws_size,
                              hipStream_t stream) {
    const int*   sent  = (const int*)d_in[0];
    // d_in[1] = transitions: unused by the reference
    const float* emb   = (const float*)d_in[2];
    const float* Wenc  = (const float*)d_in[3];
    const float* benc  = (const float*)d_in[4];
    const float* Wcomp = (const float*)d_in[5];
    const float* bcomp = (const float*)d_in[6];
    const float* Wsel1 = (const float*)d_in[7];
    const float* bs1   = (const float*)d_in[8];
    const float* Ws2   = (const float*)d_in[9];
    const float* bs2   = (const float*)d_in[10];
    const float* Wm1   = (const float*)d_in[11];
    const float* bm1   = (const float*)d_in[12];
    const float* Wm2   = (const float*)d_in[13];
    const float* bm2   = (const float*)d_in[14];
    const float* Wout  = (const float*)d_in[15];
    const float* bout  = (const float*)d_in[16];
    float* out = (float*)d_out;

    float* ws     = (float*)d_ws;
    float* state  = ws;                              // 3,178,496 f32
    float* Ws14   = ws + 3178496;                    // 65,536
    float* logits = ws + 3244032;                    // 2*64*96 = 12,288 (ping-pong)
    int*   acts   = (int*)(ws + 3256320);            // 12,288 ints (ping-pong)
    int*   rec    = (int*)(ws + 3268608);            // 512 ints (ping-pong)
    int*   nlUsed = (int*)(ws + 3269120);            // 64 ints
    float* PselT  = ws + 3269184;                    // 2*64*2*128*16 = 524,288 (ping-pong)
    float* x1g    = ws + 3269184;                    // alias: PselT dead after scan
    float* x2g    = ws + 3334720;                    // alias

    k_encode<<<dim3(NB * 12 + 64), dim3(256), 0, stream>>>(sent, emb, Wenc, benc, state,
                                                           Wsel1, Ws14);
    k_logits0<<<dim3(NB * 5), dim3(256), 0, stream>>>(state, Ws14, bs1, Ws2, bs2, logits,
                                                      acts, rec);

    for (int t = 0; t < SS - 1; t++)   // t = 0..94
        k_step<<<dim3(256), dim3(640), 0, stream>>>(Wcomp, bcomp, Ws14, bs1, Ws2, bs2,
                                                    logits, acts, rec, nlUsed, PselT, state, t);

    k_mlp1<<<dim3(NB * 4), dim3(256), 0, stream>>>(state, nlUsed, Wm1, bm1, x1g);
    k_mlp2<<<dim3(256), dim3(128), 0, stream>>>(x1g, Wm2, bm2, x2g);
    k_mlp3<<<dim3(NB), dim3(256), 0, stream>>>(x2g, Wout, bout, out);
}

// Round 14
// 1174.433 us; speedup vs baseline: 1.0678x; 1.0271x over previous
//
#include <hip/hip_runtime.h>
#include <math.h>

#define NB   64
#define SS   96
#define EE   300
#define DD   512
#define HH   256
#define SELD 128
#define CK   1280   // 5*H
#define MLPD 1024
#define NCLS 3
#define RB   97     // state rows per batch: 96 initial + 1 spare (freed-row recycling)

// ---------------- encode v6 (proven 72us) + folded W_sel1 transpose (blocks >= NB*12) -----------
__global__ __launch_bounds__(256) void k_encode(const int* __restrict__ sent,
                                                const float* __restrict__ emb,
                                                const float* __restrict__ Wenc,
                                                const float* __restrict__ benc,
                                                float* __restrict__ state,
                                                const float* __restrict__ Ws,
                                                float* __restrict__ Ws4) {
    int bi = blockIdx.x;
    int tid = threadIdx.x;
    if (bi >= NB * 12) {                          // W_sel1 transpose: 64 blocks x 2 e4-rows
        int e4 = (bi - NB * 12) * 2 + (tid >> 7);
        int k = tid & 127;
        float4 v;
        v.x = Ws[(4 * e4 + 0) * SELD + k];
        v.y = Ws[(4 * e4 + 1) * SELD + k];
        v.z = Ws[(4 * e4 + 2) * SELD + k];
        v.w = Ws[(4 * e4 + 3) * SELD + k];
        ((float4*)Ws4)[e4 * SELD + k] = v;
        return;
    }
    int b = bi / 12, rem = bi % 12, tile = rem >> 2, ch = rem & 3;
    int s0 = tile * 32, col0 = ch * 128;
    __shared__ int tok[32];
    __shared__ __align__(16) float elds[32 * 300];
    if (tid < 32) tok[tid] = sent[b * SS + s0 + tid];
    __syncthreads();
    {
        const float4* e4p = (const float4*)emb;
        float4* l4s = (float4*)elds;
        for (int i4 = tid; i4 < 32 * 75; i4 += 256) {
            int s = i4 / 75, r = i4 - s * 75;
            l4s[i4] = e4p[(size_t)tok[s] * 75 + r];
        }
    }
    __syncthreads();
    int cg = tid & 15, sg = tid >> 4;
    int colb = col0 + cg * 8, sb = sg * 2;
    float4 aA0, aA1, aB0, aB1;
    {
        float4 bA = *(const float4*)&benc[colb];
        float4 bB = *(const float4*)&benc[colb + 4];
        aA0 = bA; aA1 = bA; aB0 = bB; aB1 = bB;
    }
    const float4* l4 = (const float4*)elds;
    for (int e4 = 0; e4 < 75; e4++) {
        float4 wA[4], wB[4];
#pragma unroll
        for (int j = 0; j < 4; j++) {
            const float* wr = Wenc + (size_t)(4 * e4 + j) * DD + colb;
            wA[j] = *(const float4*)wr;
            wB[j] = *(const float4*)(wr + 4);
        }
        float4 x0 = l4[(sb + 0) * 75 + e4];
        float4 x1 = l4[(sb + 1) * 75 + e4];
        aA0.x += x0.x * wA[0].x + x0.y * wA[1].x + x0.z * wA[2].x + x0.w * wA[3].x;
        aA0.y += x0.x * wA[0].y + x0.y * wA[1].y + x0.z * wA[2].y + x0.w * wA[3].y;
        aA0.z += x0.x * wA[0].z + x0.y * wA[1].z + x0.z * wA[2].z + x0.w * wA[3].z;
        aA0.w += x0.x * wA[0].w + x0.y * wA[1].w + x0.z * wA[2].w + x0.w * wA[3].w;
        aB0.x += x0.x * wB[0].x + x0.y * wB[1].x + x0.z * wB[2].x + x0.w * wB[3].x;
        aB0.y += x0.x * wB[0].y + x0.y * wB[1].y + x0.z * wB[2].y + x0.w * wB[3].y;
        aB0.z += x0.x * wB[0].z + x0.y * wB[1].z + x0.z * wB[2].z + x0.w * wB[3].z;
        aB0.w += x0.x * wB[0].w + x0.y * wB[1].w + x0.z * wB[2].w + x0.w * wB[3].w;
        aA1.x += x1.x * wA[0].x + x1.y * wA[1].x + x1.z * wA[2].x + x1.w * wA[3].x;
        aA1.y += x1.x * wA[0].y + x1.y * wA[1].y + x1.z * wA[2].y + x1.w * wA[3].y;
        aA1.z += x1.x * wA[0].z + x1.y * wA[1].z + x1.z * wA[2].z + x1.w * wA[3].z;
        aA1.w += x1.x * wA[0].w + x1.y * wA[1].w + x1.z * wA[2].w + x1.w * wA[3].w;
        aB1.x += x1.x * wB[0].x + x1.y * wB[1].x + x1.z * wB[2].x + x1.w * wB[3].x;
        aB1.y += x1.x * wB[0].y + x1.y * wB[1].y + x1.z * wB[2].y + x1.w * wB[3].y;
        aB1.z += x1.x * wB[0].z + x1.y * wB[1].z + x1.z * wB[2].z + x1.w * wB[3].z;
        aB1.w += x1.x * wB[0].w + x1.y * wB[1].w + x1.z * wB[2].w + x1.w * wB[3].w;
    }
    {
        float* dst = state + ((size_t)b * RB + s0 + sb) * DD + colb;
        *(float4*)dst = aA0;
        *(float4*)(dst + 4) = aB0;
        dst += DD;
        *(float4*)dst = aA1;
        *(float4*)(dst + 4) = aB1;
    }
}

// ---------------- initial logits (R8, proven) + folded bookkeeping init --------------------------
__global__ __launch_bounds__(256) void k_logits0(const float* __restrict__ state,
                                                 const float* __restrict__ Ws4,
                                                 const float* __restrict__ bs1,
                                                 const float* __restrict__ Ws2,
                                                 const float* __restrict__ bs2,
                                                 float* __restrict__ logits,
                                                 int* __restrict__ acts,
                                                 int* __restrict__ rec) {
    int b = blockIdx.x / 5, tile = blockIdx.x % 5, p0 = tile * 19;
    __shared__ __align__(16) float hl[20 * 256];
    __shared__ float part[2][2][10];
    int tid = threadIdx.x;
    if (tile == 0) {                              // parity-0 bookkeeping init
        if (tid < SS) acts[b * SS + tid] = tid;
        if (tid == 0) {
            int* r = rec + b * 4;
            r[0] = 0; r[1] = 0; r[2] = 0; r[3] = SS;
        }
    }
    for (int i = tid; i < 20 * 256; i += 256) {
        int r = i >> 8, c = i & 255;
        hl[i] = state[((size_t)b * RB + p0 + r) * DD + HH + c];
    }
    __syncthreads();
    int k = tid & 127, ph = tid >> 7;
    int npair = ph ? 9 : 10, pbase = ph * 10;
    float acc[10];
#pragma unroll
    for (int pp = 0; pp < 10; pp++) acc[pp] = 0.f;
    const float4* W4 = (const float4*)Ws4;
    const float4* h4 = (const float4*)hl;
    for (int e4 = 0; e4 < 128; e4++) {
        float4 w = W4[e4 * SELD + k];
#pragma unroll
        for (int pp = 0; pp < 10; pp++) {
            float4 x = h4[(pbase + pp) * 64 + e4];
            acc[pp] += x.x * w.x + x.y * w.y + x.z * w.z + x.w * w.w;
        }
    }
    float b1 = bs1[k], w2 = Ws2[k];
    int wid = (tid >> 6) & 1, lane = tid & 63;
#pragma unroll
    for (int pp = 0; pp < 10; pp++) {
        float y = (pp < npair) ? tanhf(acc[pp] + b1) * w2 : 0.f;
        for (int off = 32; off >= 1; off >>= 1) y += __shfl_down(y, off);
        if (lane == 0 && pp < npair) part[ph][wid][pp] = y;
    }
    __syncthreads();
    if (tid < 19) {
        int ph2 = tid / 10, pp = tid - ph2 * 10;
        logits[b * SS + p0 + tid] = part[ph2][0][pp] + part[ph2][1][pp] + bs2[0];
    }
}

// ---------------- fused step kernel v8 (R12, kept): role-split sel-partial tail ------------------
// 256 blocks = 16 bg x 16 ut; 640 threads; 4 batches/block.
// PselT layout per (parity,b): [pair(2)][k(128)][ut(16)] floats.
__global__ __launch_bounds__(640) void k_step(const float* __restrict__ Wc,
                                              const float* __restrict__ bcomp,
                                              const float* __restrict__ Ws4,
                                              const float* __restrict__ bs1,
                                              const float* __restrict__ Ws2,
                                              const float* __restrict__ bs2,
                                              float* __restrict__ logits,
                                              int* __restrict__ acts,
                                              int* __restrict__ rec,
                                              int* __restrict__ nlUsed,
                                              float* __restrict__ PselT,
                                              float* __restrict__ state, int t) {
    int bg = blockIdx.x & 15, ut = blockIdx.x >> 4;
    int tid = threadIdx.x, w = tid >> 6, lane = tid & 63;
    int n = SS - t, p = t & 1, np = p ^ 1;

    __shared__ float lgl[4][SS];
    __shared__ int   acl[4][SS];
    __shared__ int   recl[4][8];                 // idx,l,r,nl,lm1,r2,v0,v1
    __shared__ float cl[4][16], cr[4][16], lm1s[4][16], r2s[4][16], hn[4][16];
    __shared__ __align__(16) float4 sp4[4][20][33];
    __shared__ float a_l[4][5][16];
    __shared__ float pstat[4][2][SELD];          // [b][pair][k] static halves

    // ---- prefetch Ws4 fragments per role ----
    float4 pw0, pw1, pw2, pw3;
    {
        int role = (tid < 256) ? tid : ((tid >= 384) ? (tid - 384) : 0);
        int kk = role & 127, rh = role >> 7;
        int half = (tid < 256) ? (rh ^ 1) : rh;
        int e4base = half * 64 + ut * 4;
        const float4* W4 = (const float4*)Ws4;
        pw0 = W4[(size_t)(e4base + 0) * SELD + kk];
        pw1 = W4[(size_t)(e4base + 1) * SELD + kk];
        pw2 = W4[(size_t)(e4base + 2) * SELD + kk];
        pw3 = W4[(size_t)(e4base + 3) * SELD + kk];
    }

    // ---- merged phases 1+2: hole refresh in registers, patch, argmax ----
    if (tid < 256) {
        int b = bg * 4 + w;
        const float* lgp = logits + ((size_t)p * NB + b) * SS;
        const int* acp = acts + ((size_t)p * NB + b) * SS;
        int4 r4 = *(const int4*)(rec + ((size_t)p * NB + b) * 4);
        int pidx = r4.x, pv0 = r4.y, pv1 = r4.z, freerow = r4.w;
        int j0 = lane, j1 = lane + 64;
        float x0v = (j0 <= n - 2) ? lgp[j0] : -3.0e38f;
        float x1v = (j1 <= n - 2) ? lgp[j1] : -3.0e38f;
        acl[w][j0] = acp[j0];
        if (j1 < SS) acl[w][j1] = acp[j1];
        if (t > 0 && (pv0 | pv1)) {
            float bs2v = bs2[0];
            float sA0 = bs1[lane], sA1 = bs1[lane + 64];
            float sB0 = sA0, sB1 = sA1;
            const float4* Pb4 = (const float4*)(PselT + (size_t)(p * NB + b) * 2 * 2048);
            float4 vA0, vA1, vB0, vB1;
#pragma unroll
            for (int c = 0; c < 4; c++) {
                vA0 = Pb4[lane * 4 + c];
                vA1 = Pb4[(lane + 64) * 4 + c];
                vB0 = Pb4[512 + lane * 4 + c];
                vB1 = Pb4[512 + (lane + 64) * 4 + c];
                sA0 += vA0.x + vA0.y + vA0.z + vA0.w;
                sA1 += vA1.x + vA1.y + vA1.z + vA1.w;
                sB0 += vB0.x + vB0.y + vB0.z + vB0.w;
                sB1 += vB1.x + vB1.y + vB1.z + vB1.w;
            }
            float yA = tanhf(sA0) * Ws2[lane] + tanhf(sA1) * Ws2[lane + 64];
            float yB = tanhf(sB0) * Ws2[lane] + tanhf(sB1) * Ws2[lane + 64];
#pragma unroll
            for (int off = 1; off < 64; off <<= 1) {
                yA += __shfl_xor(yA, off);
                yB += __shfl_xor(yB, off);
            }
            yA += bs2v; yB += bs2v;
            if (pv0) { if (j0 == pidx - 1) x0v = yA; if (j1 == pidx - 1) x1v = yA; }
            if (pv1) { if (j0 == pidx)     x0v = yB; if (j1 == pidx)     x1v = yB; }
        }
        if (j0 <= n - 2) lgl[w][j0] = x0v;
        if (j1 <= n - 2) lgl[w][j1] = x1v;
        float v = x0v; int i = j0;
        if (x1v > v) { v = x1v; i = j1; }
#pragma unroll
        for (int off = 1; off < 64; off <<= 1) {
            float ov = __shfl_xor(v, off);
            int oi = __shfl_xor(i, off);
            if (ov > v || (ov == v && oi < i)) { v = ov; i = oi; }
        }
        if (lane == 0) {
            int idx2 = i, l = acl[w][idx2], r = acl[w][idx2 + 1];
            int v0 = (idx2 >= 1), v1 = (idx2 <= n - 3);
            recl[w][0] = idx2; recl[w][1] = l; recl[w][2] = r; recl[w][3] = freerow;
            recl[w][4] = v0 ? acl[w][idx2 - 1] : 0;
            recl[w][5] = v1 ? acl[w][idx2 + 2] : 0;
            recl[w][6] = v0; recl[w][7] = v1;
        }
    }
    __syncthreads();

    // ---- stage small slices (c of l/r; h-slices of lm1/r2) ----
    if (tid < 256) {
        int which = tid >> 6, b2 = (tid >> 4) & 3, u = tid & 15;
        const float* sb = state + (size_t)(bg * 4 + b2) * RB * DD;
        if (which == 0)      cl[b2][u]   = sb[(size_t)recl[b2][1] * DD + ut * 16 + u];
        else if (which == 1) cr[b2][u]   = sb[(size_t)recl[b2][2] * DD + ut * 16 + u];
        else if (which == 2) lm1s[b2][u] = sb[(size_t)recl[b2][4] * DD + HH + ut * 16 + u];
        else                 r2s[b2][u]  = sb[(size_t)recl[b2][5] * DD + HH + ut * 16 + u];
    }

    // ---- bookkeeping into parity t+1 (ut==0 blocks; overlaps matvec) ----
    if (ut == 0 && tid < 256) {
        int b = bg * 4 + w;
        int idx = recl[w][0], l = recl[w][1], nl = recl[w][3];
        int* acn = acts + ((size_t)np * NB + b) * SS;
        float* lgn = logits + ((size_t)np * NB + b) * SS;
        for (int j = lane; j <= n - 2; j += 64)
            acn[j] = (j < idx) ? acl[w][j] : ((j == idx) ? nl : acl[w][j + 1]);
        for (int j = lane; j <= n - 3; j += 64)
            if (j != idx - 1 && j != idx)
                lgn[j] = (j < idx - 1) ? lgl[w][j] : lgl[w][j + 1];
        if (lane == 0) {
            int* rn = rec + ((size_t)np * NB + b) * 4;
            rn[0] = idx; rn[1] = recl[w][6]; rn[2] = recl[w][7]; rn[3] = l;
            nlUsed[b] = nl;
        }
    }

    // ---- compose matvec: thread = (ks:32, cq:20); 4 batches in regs ----
    {
        int ks = tid / 20, cq = tid - (tid / 20) * 20;
        int g = cq >> 2, q = cq & 3;
        int colb = g * 256 + ut * 16 + q * 4;
        int hoff = (ks & 15) * 4;
        bool leftHalf = (ks < 16);
        const float4* xp0 = (const float4*)(state + ((size_t)(bg * 4 + 0) * RB +
                              (leftHalf ? recl[0][1] : recl[0][2])) * DD + HH) + hoff;
        const float4* xp1 = (const float4*)(state + ((size_t)(bg * 4 + 1) * RB +
                              (leftHalf ? recl[1][1] : recl[1][2])) * DD + HH) + hoff;
        const float4* xp2 = (const float4*)(state + ((size_t)(bg * 4 + 2) * RB +
                              (leftHalf ? recl[2][1] : recl[2][2])) * DD + HH) + hoff;
        const float4* xp3 = (const float4*)(state + ((size_t)(bg * 4 + 3) * RB +
                              (leftHalf ? recl[3][1] : recl[3][2])) * DD + HH) + hoff;
        const float* wb = Wc + (size_t)(ks * 16) * CK + colb;
        float4 a0 = make_float4(0.f, 0.f, 0.f, 0.f);
        float4 a1 = a0, a2 = a0, a3 = a0;
#pragma unroll
        for (int i4 = 0; i4 < 4; i4++) {
            float4 xv0 = xp0[i4], xv1 = xp1[i4], xv2 = xp2[i4], xv3 = xp3[i4];
            const float* wr = wb + (size_t)(i4 * 4) * CK;
            float4 w0 = *(const float4*)(wr);
            float4 w1 = *(const float4*)(wr + CK);
            float4 w2v = *(const float4*)(wr + 2 * CK);
            float4 w3v = *(const float4*)(wr + 3 * CK);
            a0.x += xv0.x * w0.x + xv0.y * w1.x + xv0.z * w2v.x + xv0.w * w3v.x;
            a0.y += xv0.x * w0.y + xv0.y * w1.y + xv0.z * w2v.y + xv0.w * w3v.y;
            a0.z += xv0.x * w0.z + xv0.y * w1.z + xv0.z * w2v.z + xv0.w * w3v.z;
            a0.w += xv0.x * w0.w + xv0.y * w1.w + xv0.z * w2v.w + xv0.w * w3v.w;
            a1.x += xv1.x * w0.x + xv1.y * w1.x + xv1.z * w2v.x + xv1.w * w3v.x;
            a1.y += xv1.x * w0.y + xv1.y * w1.y + xv1.z * w2v.y + xv1.w * w3v.y;
            a1.z += xv1.x * w0.z + xv1.y * w1.z + xv1.z * w2v.z + xv1.w * w3v.z;
            a1.w += xv1.x * w0.w + xv1.y * w1.w + xv1.z * w2v.w + xv1.w * w3v.w;
            a2.x += xv2.x * w0.x + xv2.y * w1.x + xv2.z * w2v.x + xv2.w * w3v.x;
            a2.y += xv2.x * w0.y + xv2.y * w1.y + xv2.z * w2v.y + xv2.w * w3v.y;
            a2.z += xv2.x * w0.z + xv2.y * w1.z + xv2.z * w2v.z + xv2.w * w3v.z;
            a2.w += xv2.x * w0.w + xv2.y * w1.w + xv2.z * w2v.w + xv2.w * w3v.w;
            a3.x += xv3.x * w0.x + xv3.y * w1.x + xv3.z * w2v.x + xv3.w * w3v.x;
            a3.y += xv3.x * w0.y + xv3.y * w1.y + xv3.z * w2v.y + xv3.w * w3v.y;
            a3.z += xv3.x * w0.z + xv3.y * w1.z + xv3.z * w2v.z + xv3.w * w3v.z;
            a3.w += xv3.x * w0.w + xv3.y * w1.w + xv3.z * w2v.w + xv3.w * w3v.w;
        }
        sp4[0][cq][ks] = a0;
        sp4[1][cq][ks] = a1;
        sp4[2][cq][ks] = a2;
        sp4[3][cq][ks] = a3;
    }
    __syncthreads();

    // ---- K-reduce (tid<320) IN PARALLEL WITH static sel halves (tid>=384) ----
    if (tid < 320) {
        int b = tid / 80, colIdx = tid % 80;
        int g = colIdx >> 4, u = colIdx & 15;
        int cq = colIdx >> 2, e = colIdx & 3;
        float a = 0.f;
#pragma unroll
        for (int ks2 = 0; ks2 < 32; ks2++) a += ((const float*)&sp4[b][cq][ks2])[e];
        a_l[b][g][u] = a + bcomp[g * 256 + ut * 16 + u];
    } else if (tid >= 384) {
        int r = tid - 384, kk = r & 127, sh = r >> 7;   // sh==pair: 0->lm1 half, 1->r2 half
#pragma unroll
        for (int b4 = 0; b4 < 4; b4++) {
            const float* xs = sh ? r2s[b4] : lm1s[b4];
            float s = pw0.x * xs[0] + pw0.y * xs[1] + pw0.z * xs[2] + pw0.w * xs[3]
                    + pw1.x * xs[4] + pw1.y * xs[5] + pw1.z * xs[6] + pw1.w * xs[7]
                    + pw2.x * xs[8] + pw2.y * xs[9] + pw2.z * xs[10] + pw2.w * xs[11]
                    + pw3.x * xs[12] + pw3.y * xs[13] + pw3.z * xs[14] + pw3.w * xs[15];
            pstat[b4][sh][kk] = s;
        }
    }
    __syncthreads();

    // ---- gates + write composed c,h into fresh row ----
    if (tid < 64) {
        int b = tid >> 4, u = tid & 15;
        float ai = a_l[b][0][u], afl = a_l[b][1][u], afr = a_l[b][2][u];
        float ao = a_l[b][3][u], agc = a_l[b][4][u];
        float si  = 1.f / (1.f + expf(-ai));
        float sfl = 1.f / (1.f + expf(-afl));
        float sfr = 1.f / (1.f + expf(-afr));
        float so  = 1.f / (1.f + expf(-ao));
        float cv = sfl * cl[b][u] + sfr * cr[b][u] + si * tanhf(agc);
        float hv = so * tanhf(cv);
        float* sb = state + (size_t)(bg * 4 + b) * RB * DD;
        int nl = recl[b][3];
        sb[(size_t)nl * DD + ut * 16 + u] = cv;
        sb[(size_t)nl * DD + HH + ut * 16 + u] = hv;
        hn[b][u] = hv;
    }
    __syncthreads();

    // ---- dynamic (hn) sel halves + combine + write PselT ----
    if (tid < 256) {
        int kk = tid & 127, dh = tid >> 7;           // dh == pair index
#pragma unroll
        for (int b4 = 0; b4 < 4; b4++) {
            const float* xh = hn[b4];
            float d = pw0.x * xh[0] + pw0.y * xh[1] + pw0.z * xh[2] + pw0.w * xh[3]
                    + pw1.x * xh[4] + pw1.y * xh[5] + pw1.z * xh[6] + pw1.w * xh[7]
                    + pw2.x * xh[8] + pw2.y * xh[9] + pw2.z * xh[10] + pw2.w * xh[11]
                    + pw3.x * xh[12] + pw3.y * xh[13] + pw3.z * xh[14] + pw3.w * xh[15];
            int b = bg * 4 + b4;
            PselT[((size_t)(np * NB + b) * 2 + dh) * 2048 + kk * 16 + ut] =
                d + pstat[b4][dh][kk];
        }
    }
}

// ---------------- MLP head, column-parallel ------------------------------------------------------
__global__ __launch_bounds__(256) void k_mlp1(const float* __restrict__ state,
                                              const int* __restrict__ nlUsed,
                                              const float* __restrict__ Wm1,
                                              const float* __restrict__ bm1,
                                              float* __restrict__ x1g) {
    int b = blockIdx.x >> 2, q = blockIdx.x & 3, tid = threadIdx.x;
    int col = q * 256 + tid;
    __shared__ float x0[HH];
    int root = nlUsed[b];
    x0[tid] = state[((size_t)b * RB + root) * DD + HH + tid];
    __syncthreads();
    float acc = bm1[col];
    for (int e = 0; e < HH; e++) acc += x0[e] * Wm1[(size_t)e * MLPD + col];
    x1g[(size_t)b * MLPD + col] = fmaxf(acc, 0.f);
}

// mlp2 v3: 512 blocks = 64 b x 8 col-slices; 256 threads = 2-way e-split x 128 cols.
__global__ __launch_bounds__(256) void k_mlp2(const float* __restrict__ x1g,
                                              const float* __restrict__ Wm2,
                                              const float* __restrict__ bm2,
                                              float* __restrict__ x2g) {
    int b = blockIdx.x >> 3, q = blockIdx.x & 7, tid = threadIdx.x;
    int col = q * 128 + (tid & 127), es = tid >> 7;
    __shared__ __align__(16) float x1[MLPD];
    __shared__ float partial[2][128];
    for (int i = tid; i < 256; i += 256)
        ((float4*)x1)[i] = ((const float4*)(x1g + (size_t)b * MLPD))[i];
    __syncthreads();
    float acc = 0.f;
    for (int e = es * 512; e < es * 512 + 512; e++)
        acc += x1[e] * Wm2[(size_t)e * MLPD + col];
    partial[es][tid & 127] = acc;
    __syncthreads();
    if (tid < 128)
        x2g[(size_t)b * MLPD + q * 128 + tid] =
            fmaxf(partial[0][tid] + partial[1][tid] + bm2[q * 128 + tid], 0.f);
}

__global__ __launch_bounds__(256) void k_mlp3(const float* __restrict__ x2g,
                                              const float* __restrict__ Wout,
                                              const float* __restrict__ bout,
                                              float* __restrict__ out) {
    int b = blockIdx.x, tid = threadIdx.x;
    __shared__ __align__(16) float x2[MLPD];
    __shared__ float red3[3][256];
    ((float4*)x2)[tid] = ((const float4*)(x2g + (size_t)b * MLPD))[tid];
    __syncthreads();
    float p0 = 0.f, p1 = 0.f, p2 = 0.f;
    for (int e = tid; e < MLPD; e += 256) {
        float x = x2[e];
        p0 += x * Wout[e * NCLS + 0];
        p1 += x * Wout[e * NCLS + 1];
        p2 += x * Wout[e * NCLS + 2];
    }
    red3[0][tid] = p0; red3[1][tid] = p1; red3[2][tid] = p2;
    __syncthreads();
    for (int sdd = 128; sdd >= 1; sdd >>= 1) {
        if (tid < sdd) {
            red3[0][tid] += red3[0][tid + sdd];
            red3[1][tid] += red3[1][tid + sdd];
            red3[2][tid] += red3[2][tid + sdd];
        }
        __syncthreads();
    }
    if (tid < NCLS) out[b * NCLS + tid] = red3[tid][0] + bout[tid];
}

extern "C" void kernel_launch(void* const* d_in, const int* in_sizes, int n_in,
                              void* d_out, int out_size, void* d_ws, size_t ws_size,
                              hipStream_t stream) {
    const int*   sent  = (const int*)d_in[0];
    // d_in[1] = transitions: unused by the reference
    const float* emb   = (const float*)d_in[2];
    const float* Wenc  = (const float*)d_in[3];
    const float* benc  = (const float*)d_in[4];
    const float* Wcomp = (const float*)d_in[5];
    const float* bcomp = (const float*)d_in[6];
    const float* Wsel1 = (const float*)d_in[7];
    const float* bs1   = (const float*)d_in[8];
    const float* Ws2   = (const float*)d_in[9];
    const float* bs2   = (const float*)d_in[10];
    const float* Wm1   = (const float*)d_in[11];
    const float* bm1   = (const float*)d_in[12];
    const float* Wm2   = (const float*)d_in[13];
    const float* bm2   = (const float*)d_in[14];
    const float* Wout  = (const float*)d_in[15];
    const float* bout  = (const float*)d_in[16];
    float* out = (float*)d_out;

    float* ws     = (float*)d_ws;
    float* state  = ws;                              // 3,178,496 f32
    float* Ws14   = ws + 3178496;                    // 65,536
    float* logits = ws + 3244032;                    // 2*64*96 = 12,288 (ping-pong)
    int*   acts   = (int*)(ws + 3256320);            // 12,288 ints (ping-pong)
    int*   rec    = (int*)(ws + 3268608);            // 512 ints (ping-pong)
    int*   nlUsed = (int*)(ws + 3269120);            // 64 ints
    float* PselT  = ws + 3269184;                    // 2*64*2*128*16 = 524,288 (ping-pong)
    float* x1g    = ws + 3269184;                    // alias: PselT dead after scan
    float* x2g    = ws + 3334720;                    // alias

    k_encode<<<dim3(NB * 12 + 64), dim3(256), 0, stream>>>(sent, emb, Wenc, benc, state,
                                                           Wsel1, Ws14);
    k_logits0<<<dim3(NB * 5), dim3(256), 0, stream>>>(state, Ws14, bs1, Ws2, bs2, logits,
                                                      acts, rec);

    for (int t = 0; t < SS - 1; t++)   // t = 0..94
        k_step<<<dim3(256), dim3(640), 0, stream>>>(Wcomp, bcomp, Ws14, bs1, Ws2, bs2,
                                                    logits, acts, rec, nlUsed, PselT, state, t);

    k_mlp1<<<dim3(NB * 4), dim3(256), 0, stream>>>(state, nlUsed, Wm1, bm1, x1g);
    k_mlp2<<<dim3(512), dim3(256), 0, stream>>>(x1g, Wm2, bm2, x2g);
    k_mlp3<<<dim3(NB), dim3(256), 0, stream>>>(x2g, Wout, bout, out);
}

// Round 15
// 1170.092 us; speedup vs baseline: 1.0718x; 1.0037x over previous
//
#include <hip/hip_runtime.h>
#include <math.h>

#define NB   64
#define SS   96
#define EE   300
#define DD   512
#define HH   256
#define SELD 128
#define CK   1280   // 5*H
#define MLPD 1024
#define NCLS 3
#define RB   97     // state rows per batch: 96 initial + 1 spare (freed-row recycling)

// ---------------- encode v8: v6 + 2-stage W prefetch pipeline; folded W_sel1 transpose ----------
__global__ __launch_bounds__(256) void k_encode(const int* __restrict__ sent,
                                                const float* __restrict__ emb,
                                                const float* __restrict__ Wenc,
                                                const float* __restrict__ benc,
                                                float* __restrict__ state,
                                                const float* __restrict__ Ws,
                                                float* __restrict__ Ws4) {
    int bi = blockIdx.x;
    int tid = threadIdx.x;
    if (bi >= NB * 12) {                          // W_sel1 transpose: 64 blocks x 2 e4-rows
        int e4 = (bi - NB * 12) * 2 + (tid >> 7);
        int k = tid & 127;
        float4 v;
        v.x = Ws[(4 * e4 + 0) * SELD + k];
        v.y = Ws[(4 * e4 + 1) * SELD + k];
        v.z = Ws[(4 * e4 + 2) * SELD + k];
        v.w = Ws[(4 * e4 + 3) * SELD + k];
        ((float4*)Ws4)[e4 * SELD + k] = v;
        return;
    }
    int b = bi / 12, rem = bi % 12, tile = rem >> 2, ch = rem & 3;
    int s0 = tile * 32, col0 = ch * 128;
    __shared__ int tok[32];
    __shared__ __align__(16) float elds[32 * 300];
    if (tid < 32) tok[tid] = sent[b * SS + s0 + tid];
    __syncthreads();
    {
        const float4* e4p = (const float4*)emb;
        float4* l4s = (float4*)elds;
        for (int i4 = tid; i4 < 32 * 75; i4 += 256) {
            int s = i4 / 75, r = i4 - s * 75;
            l4s[i4] = e4p[(size_t)tok[s] * 75 + r];
        }
    }
    __syncthreads();
    int cg = tid & 15, sg = tid >> 4;
    int colb = col0 + cg * 8, sb = sg * 2;
    float4 aA0, aA1, aB0, aB1;
    {
        float4 bA = *(const float4*)&benc[colb];
        float4 bB = *(const float4*)&benc[colb + 4];
        aA0 = bA; aA1 = bA; aB0 = bB; aB1 = bB;
    }
    const float4* l4 = (const float4*)elds;
    float4 wA[4], wB[4], wAn[4], wBn[4];
#pragma unroll
    for (int j = 0; j < 4; j++) {
        const float* wr = Wenc + (size_t)j * DD + colb;
        wA[j] = *(const float4*)wr;
        wB[j] = *(const float4*)(wr + 4);
    }
    for (int e4 = 0; e4 < 75; e4++) {
        if (e4 < 74) {
#pragma unroll
            for (int j = 0; j < 4; j++) {
                const float* wr = Wenc + (size_t)(4 * (e4 + 1) + j) * DD + colb;
                wAn[j] = *(const float4*)wr;
                wBn[j] = *(const float4*)(wr + 4);
            }
        }
        float4 x0 = l4[(sb + 0) * 75 + e4];
        float4 x1 = l4[(sb + 1) * 75 + e4];
        aA0.x += x0.x * wA[0].x + x0.y * wA[1].x + x0.z * wA[2].x + x0.w * wA[3].x;
        aA0.y += x0.x * wA[0].y + x0.y * wA[1].y + x0.z * wA[2].y + x0.w * wA[3].y;
        aA0.z += x0.x * wA[0].z + x0.y * wA[1].z + x0.z * wA[2].z + x0.w * wA[3].z;
        aA0.w += x0.x * wA[0].w + x0.y * wA[1].w + x0.z * wA[2].w + x0.w * wA[3].w;
        aB0.x += x0.x * wB[0].x + x0.y * wB[1].x + x0.z * wB[2].x + x0.w * wB[3].x;
        aB0.y += x0.x * wB[0].y + x0.y * wB[1].y + x0.z * wB[2].y + x0.w * wB[3].y;
        aB0.z += x0.x * wB[0].z + x0.y * wB[1].z + x0.z * wB[2].z + x0.w * wB[3].z;
        aB0.w += x0.x * wB[0].w + x0.y * wB[1].w + x0.z * wB[2].w + x0.w * wB[3].w;
        aA1.x += x1.x * wA[0].x + x1.y * wA[1].x + x1.z * wA[2].x + x1.w * wA[3].x;
        aA1.y += x1.x * wA[0].y + x1.y * wA[1].y + x1.z * wA[2].y + x1.w * wA[3].y;
        aA1.z += x1.x * wA[0].z + x1.y * wA[1].z + x1.z * wA[2].z + x1.w * wA[3].z;
        aA1.w += x1.x * wA[0].w + x1.y * wA[1].w + x1.z * wA[2].w + x1.w * wA[3].w;
        aB1.x += x1.x * wB[0].x + x1.y * wB[1].x + x1.z * wB[2].x + x1.w * wB[3].x;
        aB1.y += x1.x * wB[0].y + x1.y * wB[1].y + x1.z * wB[2].y + x1.w * wB[3].y;
        aB1.z += x1.x * wB[0].z + x1.y * wB[1].z + x1.z * wB[2].z + x1.w * wB[3].z;
        aB1.w += x1.x * wB[0].w + x1.y * wB[1].w + x1.z * wB[2].w + x1.w * wB[3].w;
#pragma unroll
        for (int j = 0; j < 4; j++) { wA[j] = wAn[j]; wB[j] = wBn[j]; }
    }
    {
        float* dst = state + ((size_t)b * RB + s0 + sb) * DD + colb;
        *(float4*)dst = aA0;
        *(float4*)(dst + 4) = aB0;
        dst += DD;
        *(float4*)dst = aA1;
        *(float4*)(dst + 4) = aB1;
    }
}

// ---------------- initial logits (R8, proven) + folded bookkeeping init --------------------------
__global__ __launch_bounds__(256) void k_logits0(const float* __restrict__ state,
                                                 const float* __restrict__ Ws4,
                                                 const float* __restrict__ bs1,
                                                 const float* __restrict__ Ws2,
                                                 const float* __restrict__ bs2,
                                                 float* __restrict__ logits,
                                                 int* __restrict__ acts,
                                                 int* __restrict__ rec) {
    int b = blockIdx.x / 5, tile = blockIdx.x % 5, p0 = tile * 19;
    __shared__ __align__(16) float hl[20 * 256];
    __shared__ float part[2][2][10];
    int tid = threadIdx.x;
    if (tile == 0) {                              // parity-0 bookkeeping init
        if (tid < SS) acts[b * SS + tid] = tid;
        if (tid == 0) {
            int* r = rec + b * 4;
            r[0] = 0; r[1] = 0; r[2] = 0; r[3] = SS;
        }
    }
    for (int i = tid; i < 20 * 256; i += 256) {
        int r = i >> 8, c = i & 255;
        hl[i] = state[((size_t)b * RB + p0 + r) * DD + HH + c];
    }
    __syncthreads();
    int k = tid & 127, ph = tid >> 7;
    int npair = ph ? 9 : 10, pbase = ph * 10;
    float acc[10];
#pragma unroll
    for (int pp = 0; pp < 10; pp++) acc[pp] = 0.f;
    const float4* W4 = (const float4*)Ws4;
    const float4* h4 = (const float4*)hl;
    for (int e4 = 0; e4 < 128; e4++) {
        float4 w = W4[e4 * SELD + k];
#pragma unroll
        for (int pp = 0; pp < 10; pp++) {
            float4 x = h4[(pbase + pp) * 64 + e4];
            acc[pp] += x.x * w.x + x.y * w.y + x.z * w.z + x.w * w.w;
        }
    }
    float b1 = bs1[k], w2 = Ws2[k];
    int wid = (tid >> 6) & 1, lane = tid & 63;
#pragma unroll
    for (int pp = 0; pp < 10; pp++) {
        float y = (pp < npair) ? tanhf(acc[pp] + b1) * w2 : 0.f;
        for (int off = 32; off >= 1; off >>= 1) y += __shfl_down(y, off);
        if (lane == 0 && pp < npair) part[ph][wid][pp] = y;
    }
    __syncthreads();
    if (tid < 19) {
        int ph2 = tid / 10, pp = tid - ph2 * 10;
        logits[b * SS + p0 + tid] = part[ph2][0][pp] + part[ph2][1][pp] + bs2[0];
    }
}

// ---------------- fused step kernel v8 (R12, kept): role-split sel-partial tail ------------------
// 256 blocks = 16 bg x 16 ut; 640 threads; 4 batches/block.
// PselT layout per (parity,b): [pair(2)][k(128)][ut(16)] floats.
__global__ __launch_bounds__(640) void k_step(const float* __restrict__ Wc,
                                              const float* __restrict__ bcomp,
                                              const float* __restrict__ Ws4,
                                              const float* __restrict__ bs1,
                                              const float* __restrict__ Ws2,
                                              const float* __restrict__ bs2,
                                              float* __restrict__ logits,
                                              int* __restrict__ acts,
                                              int* __restrict__ rec,
                                              int* __restrict__ nlUsed,
                                              float* __restrict__ PselT,
                                              float* __restrict__ state, int t) {
    int bg = blockIdx.x & 15, ut = blockIdx.x >> 4;
    int tid = threadIdx.x, w = tid >> 6, lane = tid & 63;
    int n = SS - t, p = t & 1, np = p ^ 1;

    __shared__ float lgl[4][SS];
    __shared__ int   acl[4][SS];
    __shared__ int   recl[4][8];                 // idx,l,r,nl,lm1,r2,v0,v1
    __shared__ float cl[4][16], cr[4][16], lm1s[4][16], r2s[4][16], hn[4][16];
    __shared__ __align__(16) float4 sp4[4][20][33];
    __shared__ float a_l[4][5][16];
    __shared__ float pstat[4][2][SELD];          // [b][pair][k] static halves

    // ---- prefetch Ws4 fragments per role ----
    float4 pw0, pw1, pw2, pw3;
    {
        int role = (tid < 256) ? tid : ((tid >= 384) ? (tid - 384) : 0);
        int kk = role & 127, rh = role >> 7;
        int half = (tid < 256) ? (rh ^ 1) : rh;
        int e4base = half * 64 + ut * 4;
        const float4* W4 = (const float4*)Ws4;
        pw0 = W4[(size_t)(e4base + 0) * SELD + kk];
        pw1 = W4[(size_t)(e4base + 1) * SELD + kk];
        pw2 = W4[(size_t)(e4base + 2) * SELD + kk];
        pw3 = W4[(size_t)(e4base + 3) * SELD + kk];
    }

    // ---- merged phases 1+2: hole refresh in registers, patch, argmax ----
    if (tid < 256) {
        int b = bg * 4 + w;
        const float* lgp = logits + ((size_t)p * NB + b) * SS;
        const int* acp = acts + ((size_t)p * NB + b) * SS;
        int4 r4 = *(const int4*)(rec + ((size_t)p * NB + b) * 4);
        int pidx = r4.x, pv0 = r4.y, pv1 = r4.z, freerow = r4.w;
        int j0 = lane, j1 = lane + 64;
        float x0v = (j0 <= n - 2) ? lgp[j0] : -3.0e38f;
        float x1v = (j1 <= n - 2) ? lgp[j1] : -3.0e38f;
        acl[w][j0] = acp[j0];
        if (j1 < SS) acl[w][j1] = acp[j1];
        if (t > 0 && (pv0 | pv1)) {
            float bs2v = bs2[0];
            float sA0 = bs1[lane], sA1 = bs1[lane + 64];
            float sB0 = sA0, sB1 = sA1;
            const float4* Pb4 = (const float4*)(PselT + (size_t)(p * NB + b) * 2 * 2048);
            float4 vA0, vA1, vB0, vB1;
#pragma unroll
            for (int c = 0; c < 4; c++) {
                vA0 = Pb4[lane * 4 + c];
                vA1 = Pb4[(lane + 64) * 4 + c];
                vB0 = Pb4[512 + lane * 4 + c];
                vB1 = Pb4[512 + (lane + 64) * 4 + c];
                sA0 += vA0.x + vA0.y + vA0.z + vA0.w;
                sA1 += vA1.x + vA1.y + vA1.z + vA1.w;
                sB0 += vB0.x + vB0.y + vB0.z + vB0.w;
                sB1 += vB1.x + vB1.y + vB1.z + vB1.w;
            }
            float yA = tanhf(sA0) * Ws2[lane] + tanhf(sA1) * Ws2[lane + 64];
            float yB = tanhf(sB0) * Ws2[lane] + tanhf(sB1) * Ws2[lane + 64];
#pragma unroll
            for (int off = 1; off < 64; off <<= 1) {
                yA += __shfl_xor(yA, off);
                yB += __shfl_xor(yB, off);
            }
            yA += bs2v; yB += bs2v;
            if (pv0) { if (j0 == pidx - 1) x0v = yA; if (j1 == pidx - 1) x1v = yA; }
            if (pv1) { if (j0 == pidx)     x0v = yB; if (j1 == pidx)     x1v = yB; }
        }
        if (j0 <= n - 2) lgl[w][j0] = x0v;
        if (j1 <= n - 2) lgl[w][j1] = x1v;
        float v = x0v; int i = j0;
        if (x1v > v) { v = x1v; i = j1; }
#pragma unroll
        for (int off = 1; off < 64; off <<= 1) {
            float ov = __shfl_xor(v, off);
            int oi = __shfl_xor(i, off);
            if (ov > v || (ov == v && oi < i)) { v = ov; i = oi; }
        }
        if (lane == 0) {
            int idx2 = i, l = acl[w][idx2], r = acl[w][idx2 + 1];
            int v0 = (idx2 >= 1), v1 = (idx2 <= n - 3);
            recl[w][0] = idx2; recl[w][1] = l; recl[w][2] = r; recl[w][3] = freerow;
            recl[w][4] = v0 ? acl[w][idx2 - 1] : 0;
            recl[w][5] = v1 ? acl[w][idx2 + 2] : 0;
            recl[w][6] = v0; recl[w][7] = v1;
        }
    }
    __syncthreads();

    // ---- stage small slices (c of l/r; h-slices of lm1/r2) ----
    if (tid < 256) {
        int which = tid >> 6, b2 = (tid >> 4) & 3, u = tid & 15;
        const float* sb = state + (size_t)(bg * 4 + b2) * RB * DD;
        if (which == 0)      cl[b2][u]   = sb[(size_t)recl[b2][1] * DD + ut * 16 + u];
        else if (which == 1) cr[b2][u]   = sb[(size_t)recl[b2][2] * DD + ut * 16 + u];
        else if (which == 2) lm1s[b2][u] = sb[(size_t)recl[b2][4] * DD + HH + ut * 16 + u];
        else                 r2s[b2][u]  = sb[(size_t)recl[b2][5] * DD + HH + ut * 16 + u];
    }

    // ---- bookkeeping into parity t+1 (ut==0 blocks; overlaps matvec) ----
    if (ut == 0 && tid < 256) {
        int b = bg * 4 + w;
        int idx = recl[w][0], l = recl[w][1], nl = recl[w][3];
        int* acn = acts + ((size_t)np * NB + b) * SS;
        float* lgn = logits + ((size_t)np * NB + b) * SS;
        for (int j = lane; j <= n - 2; j += 64)
            acn[j] = (j < idx) ? acl[w][j] : ((j == idx) ? nl : acl[w][j + 1]);
        for (int j = lane; j <= n - 3; j += 64)
            if (j != idx - 1 && j != idx)
                lgn[j] = (j < idx - 1) ? lgl[w][j] : lgl[w][j + 1];
        if (lane == 0) {
            int* rn = rec + ((size_t)np * NB + b) * 4;
            rn[0] = idx; rn[1] = recl[w][6]; rn[2] = recl[w][7]; rn[3] = l;
            nlUsed[b] = nl;
        }
    }

    // ---- compose matvec: thread = (ks:32, cq:20); 4 batches in regs ----
    {
        int ks = tid / 20, cq = tid - (tid / 20) * 20;
        int g = cq >> 2, q = cq & 3;
        int colb = g * 256 + ut * 16 + q * 4;
        int hoff = (ks & 15) * 4;
        bool leftHalf = (ks < 16);
        const float4* xp0 = (const float4*)(state + ((size_t)(bg * 4 + 0) * RB +
                              (leftHalf ? recl[0][1] : recl[0][2])) * DD + HH) + hoff;
        const float4* xp1 = (const float4*)(state + ((size_t)(bg * 4 + 1) * RB +
                              (leftHalf ? recl[1][1] : recl[1][2])) * DD + HH) + hoff;
        const float4* xp2 = (const float4*)(state + ((size_t)(bg * 4 + 2) * RB +
                              (leftHalf ? recl[2][1] : recl[2][2])) * DD + HH) + hoff;
        const float4* xp3 = (const float4*)(state + ((size_t)(bg * 4 + 3) * RB +
                              (leftHalf ? recl[3][1] : recl[3][2])) * DD + HH) + hoff;
        const float* wb = Wc + (size_t)(ks * 16) * CK + colb;
        float4 a0 = make_float4(0.f, 0.f, 0.f, 0.f);
        float4 a1 = a0, a2 = a0, a3 = a0;
#pragma unroll
        for (int i4 = 0; i4 < 4; i4++) {
            float4 xv0 = xp0[i4], xv1 = xp1[i4], xv2 = xp2[i4], xv3 = xp3[i4];
            const float* wr = wb + (size_t)(i4 * 4) * CK;
            float4 w0 = *(const float4*)(wr);
            float4 w1 = *(const float4*)(wr + CK);
            float4 w2v = *(const float4*)(wr + 2 * CK);
            float4 w3v = *(const float4*)(wr + 3 * CK);
            a0.x += xv0.x * w0.x + xv0.y * w1.x + xv0.z * w2v.x + xv0.w * w3v.x;
            a0.y += xv0.x * w0.y + xv0.y * w1.y + xv0.z * w2v.y + xv0.w * w3v.y;
            a0.z += xv0.x * w0.z + xv0.y * w1.z + xv0.z * w2v.z + xv0.w * w3v.z;
            a0.w += xv0.x * w0.w + xv0.y * w1.w + xv0.z * w2v.w + xv0.w * w3v.w;
            a1.x += xv1.x * w0.x + xv1.y * w1.x + xv1.z * w2v.x + xv1.w * w3v.x;
            a1.y += xv1.x * w0.y + xv1.y * w1.y + xv1.z * w2v.y + xv1.w * w3v.y;
            a1.z += xv1.x * w0.z + xv1.y * w1.z + xv1.z * w2v.z + xv1.w * w3v.z;
            a1.w += xv1.x * w0.w + xv1.y * w1.w + xv1.z * w2v.w + xv1.w * w3v.w;
            a2.x += xv2.x * w0.x + xv2.y * w1.x + xv2.z * w2v.x + xv2.w * w3v.x;
            a2.y += xv2.x * w0.y + xv2.y * w1.y + xv2.z * w2v.y + xv2.w * w3v.y;
            a2.z += xv2.x * w0.z + xv2.y * w1.z + xv2.z * w2v.z + xv2.w * w3v.z;
            a2.w += xv2.x * w0.w + xv2.y * w1.w + xv2.z * w2v.w + xv2.w * w3v.w;
            a3.x += xv3.x * w0.x + xv3.y * w1.x + xv3.z * w2v.x + xv3.w * w3v.x;
            a3.y += xv3.x * w0.y + xv3.y * w1.y + xv3.z * w2v.y + xv3.w * w3v.y;
            a3.z += xv3.x * w0.z + xv3.y * w1.z + xv3.z * w2v.z + xv3.w * w3v.z;
            a3.w += xv3.x * w0.w + xv3.y * w1.w + xv3.z * w2v.w + xv3.w * w3v.w;
        }
        sp4[0][cq][ks] = a0;
        sp4[1][cq][ks] = a1;
        sp4[2][cq][ks] = a2;
        sp4[3][cq][ks] = a3;
    }
    __syncthreads();

    // ---- K-reduce (tid<320) IN PARALLEL WITH static sel halves (tid>=384) ----
    if (tid < 320) {
        int b = tid / 80, colIdx = tid % 80;
        int g = colIdx >> 4, u = colIdx & 15;
        int cq = colIdx >> 2, e = colIdx & 3;
        float a = 0.f;
#pragma unroll
        for (int ks2 = 0; ks2 < 32; ks2++) a += ((const float*)&sp4[b][cq][ks2])[e];
        a_l[b][g][u] = a + bcomp[g * 256 + ut * 16 + u];
    } else if (tid >= 384) {
        int r = tid - 384, kk = r & 127, sh = r >> 7;   // sh==pair: 0->lm1 half, 1->r2 half
#pragma unroll
        for (int b4 = 0; b4 < 4; b4++) {
            const float* xs = sh ? r2s[b4] : lm1s[b4];
            float s = pw0.x * xs[0] + pw0.y * xs[1] + pw0.z * xs[2] + pw0.w * xs[3]
                    + pw1.x * xs[4] + pw1.y * xs[5] + pw1.z * xs[6] + pw1.w * xs[7]
                    + pw2.x * xs[8] + pw2.y * xs[9] + pw2.z * xs[10] + pw2.w * xs[11]
                    + pw3.x * xs[12] + pw3.y * xs[13] + pw3.z * xs[14] + pw3.w * xs[15];
            pstat[b4][sh][kk] = s;
        }
    }
    __syncthreads();

    // ---- gates + write composed c,h into fresh row ----
    if (tid < 64) {
        int b = tid >> 4, u = tid & 15;
        float ai = a_l[b][0][u], afl = a_l[b][1][u], afr = a_l[b][2][u];
        float ao = a_l[b][3][u], agc = a_l[b][4][u];
        float si  = 1.f / (1.f + expf(-ai));
        float sfl = 1.f / (1.f + expf(-afl));
        float sfr = 1.f / (1.f + expf(-afr));
        float so  = 1.f / (1.f + expf(-ao));
        float cv = sfl * cl[b][u] + sfr * cr[b][u] + si * tanhf(agc);
        float hv = so * tanhf(cv);
        float* sb = state + (size_t)(bg * 4 + b) * RB * DD;
        int nl = recl[b][3];
        sb[(size_t)nl * DD + ut * 16 + u] = cv;
        sb[(size_t)nl * DD + HH + ut * 16 + u] = hv;
        hn[b][u] = hv;
    }
    __syncthreads();

    // ---- dynamic (hn) sel halves + combine + write PselT ----
    if (tid < 256) {
        int kk = tid & 127, dh = tid >> 7;           // dh == pair index
#pragma unroll
        for (int b4 = 0; b4 < 4; b4++) {
            const float* xh = hn[b4];
            float d = pw0.x * xh[0] + pw0.y * xh[1] + pw0.z * xh[2] + pw0.w * xh[3]
                    + pw1.x * xh[4] + pw1.y * xh[5] + pw1.z * xh[6] + pw1.w * xh[7]
                    + pw2.x * xh[8] + pw2.y * xh[9] + pw2.z * xh[10] + pw2.w * xh[11]
                    + pw3.x * xh[12] + pw3.y * xh[13] + pw3.z * xh[14] + pw3.w * xh[15];
            int b = bg * 4 + b4;
            PselT[((size_t)(np * NB + b) * 2 + dh) * 2048 + kk * 16 + ut] =
                d + pstat[b4][dh][kk];
        }
    }
}

// ---------------- MLP head, column-parallel ------------------------------------------------------
__global__ __launch_bounds__(256) void k_mlp1(const float* __restrict__ state,
                                              const int* __restrict__ nlUsed,
                                              const float* __restrict__ Wm1,
                                              const float* __restrict__ bm1,
                                              float* __restrict__ x1g) {
    int b = blockIdx.x >> 2, q = blockIdx.x & 3, tid = threadIdx.x;
    int col = q * 256 + tid;
    __shared__ float x0[HH];
    int root = nlUsed[b];
    x0[tid] = state[((size_t)b * RB + root) * DD + HH + tid];
    __syncthreads();
    float acc = bm1[col];
    for (int e = 0; e < HH; e++) acc += x0[e] * Wm1[(size_t)e * MLPD + col];
    x1g[(size_t)b * MLPD + col] = fmaxf(acc, 0.f);
}

// mlp2 v3: 512 blocks = 64 b x 8 col-slices; 256 threads = 2-way e-split x 128 cols.
__global__ __launch_bounds__(256) void k_mlp2(const float* __restrict__ x1g,
                                              const float* __restrict__ Wm2,
                                              const float* __restrict__ bm2,
                                              float* __restrict__ x2g) {
    int b = blockIdx.x >> 3, q = blockIdx.x & 7, tid = threadIdx.x;
    int col = q * 128 + (tid & 127), es = tid >> 7;
    __shared__ __align__(16) float x1[MLPD];
    __shared__ float partial[2][128];
    for (int i = tid; i < 256; i += 256)
        ((float4*)x1)[i] = ((const float4*)(x1g + (size_t)b * MLPD))[i];
    __syncthreads();
    float acc = 0.f;
    for (int e = es * 512; e < es * 512 + 512; e++)
        acc += x1[e] * Wm2[(size_t)e * MLPD + col];
    partial[es][tid & 127] = acc;
    __syncthreads();
    if (tid < 128)
        x2g[(size_t)b * MLPD + q * 128 + tid] =
            fmaxf(partial[0][tid] + partial[1][tid] + bm2[q * 128 + tid], 0.f);
}

__global__ __launch_bounds__(256) void k_mlp3(const float* __restrict__ x2g,
                                              const float* __restrict__ Wout,
                                              const float* __restrict__ bout,
                                              float* __restrict__ out) {
    int b = blockIdx.x, tid = threadIdx.x;
    __shared__ __align__(16) float x2[MLPD];
    __shared__ float red3[3][256];
    ((float4*)x2)[tid] = ((const float4*)(x2g + (size_t)b * MLPD))[tid];
    __syncthreads();
    float p0 = 0.f, p1 = 0.f, p2 = 0.f;
    for (int e = tid; e < MLPD; e += 256) {
        float x = x2[e];
        p0 += x * Wout[e * NCLS + 0];
        p1 += x * Wout[e * NCLS + 1];
        p2 += x * Wout[e * NCLS + 2];
    }
    red3[0][tid] = p0; red3[1][tid] = p1; red3[2][tid] = p2;
    __syncthreads();
    for (int sdd = 128; sdd >= 1; sdd >>= 1) {
        if (tid < sdd) {
            red3[0][tid] += red3[0][tid + sdd];
            red3[1][tid] += red3[1][tid + sdd];
            red3[2][tid] += red3[2][tid + sdd];
        }
        __syncthreads();
    }
    if (tid < NCLS) out[b * NCLS + tid] = red3[tid][0] + bout[tid];
}

extern "C" void kernel_launch(void* const* d_in, const int* in_sizes, int n_in,
                              void* d_out, int out_size, void* d_ws, size_t ws_size,
                              hipStream_t stream) {
    const int*   sent  = (const int*)d_in[0];
    // d_in[1] = transitions: unused by the reference
    const float* emb   = (const float*)d_in[2];
    const float* Wenc  = (const float*)d_in[3];
    const float* benc  = (const float*)d_in[4];
    const float* Wcomp = (const float*)d_in[5];
    const float* bcomp = (const float*)d_in[6];
    const float* Wsel1 = (const float*)d_in[7];
    const float* bs1   = (const float*)d_in[8];
    const float* Ws2   = (const float*)d_in[9];
    const float* bs2   = (const float*)d_in[10];
    const float* Wm1   = (const float*)d_in[11];
    const float* bm1   = (const float*)d_in[12];
    const float* Wm2   = (const float*)d_in[13];
    const float* bm2   = (const float*)d_in[14];
    const float* Wout  = (const float*)d_in[15];
    const float* bout  = (const float*)d_in[16];
    float* out = (float*)d_out;

    float* ws     = (float*)d_ws;
    float* state  = ws;                              // 3,178,496 f32
    float* Ws14   = ws + 3178496;                    // 65,536
    float* logits = ws + 3244032;                    // 2*64*96 = 12,288 (ping-pong)
    int*   acts   = (int*)(ws + 3256320);            // 12,288 ints (ping-pong)
    int*   rec    = (int*)(ws + 3268608);            // 512 ints (ping-pong)
    int*   nlUsed = (int*)(ws + 3269120);            // 64 ints
    float* PselT  = ws + 3269184;                    // 2*64*2*128*16 = 524,288 (ping-pong)
    float* x1g    = ws + 3269184;                    // alias: PselT dead after scan
    float* x2g    = ws + 3334720;                    // alias

    k_encode<<<dim3(NB * 12 + 64), dim3(256), 0, stream>>>(sent, emb, Wenc, benc, state,
                                                           Wsel1, Ws14);
    k_logits0<<<dim3(NB * 5), dim3(256), 0, stream>>>(state, Ws14, bs1, Ws2, bs2, logits,
                                                      acts, rec);

    for (int t = 0; t < SS - 1; t++)   // t = 0..94
        k_step<<<dim3(256), dim3(640), 0, stream>>>(Wcomp, bcomp, Ws14, bs1, Ws2, bs2,
                                                    logits, acts, rec, nlUsed, PselT, state, t);

    k_mlp1<<<dim3(NB * 4), dim3(256), 0, stream>>>(state, nlUsed, Wm1, bm1, x1g);
    k_mlp2<<<dim3(512), dim3(256), 0, stream>>>(x1g, Wm2, bm2, x2g);
    k_mlp3<<<dim3(NB), dim3(256), 0, stream>>>(x2g, Wout, bout, out);
}